// Round 11
// baseline (1379.249 us; speedup 1.0000x reference)
//
#include <hip/hip_runtime.h>
#include <hip/hip_bf16.h>

typedef __attribute__((ext_vector_type(4))) float f32x4;
typedef __attribute__((ext_vector_type(8))) unsigned short u16x8;
typedef __attribute__((ext_vector_type(4))) unsigned short u16x4;
typedef __bf16 bf16x8 __attribute__((ext_vector_type(8)));

#define DEVFN static __device__ __forceinline__

constexpr int CB = 8, CT = 1024, CDM = 1024, CH = 16, CDH = 64, CDFF = 4096, CV = 2000, CM = 256;
constexpr int CNT = CB * CT; // 8192 tokens
constexpr int CQKV = 3072;   // fused qkv row stride
constexpr float CDN = 0.35355339059327373f;   // 64^-0.25
constexpr float CRATIO = 0.0625f;             // 256^-0.5
constexpr float CKEPS = 1e-4f;

DEVFN unsigned short f2bu(float x) {
  __hip_bfloat16 h = __float2bfloat16(x);
  return __builtin_bit_cast(unsigned short, h);
}
DEVFN float b2f(unsigned short u) {
  __hip_bfloat16 h = __builtin_bit_cast(__hip_bfloat16, u);
  return __bfloat162float(h);
}
DEVFN float wredsum(float s) {
#pragma unroll
  for (int ofs = 32; ofs; ofs >>= 1) s += __shfl_xor(s, ofs, 64);
  return s;
}
DEVFN float wredmax(float s) {
#pragma unroll
  for (int ofs = 32; ofs; ofs >>= 1) s = fmaxf(s, __shfl_xor(s, ofs, 64));
  return s;
}
DEVFN void gl_lds16(const void* g, void* l) {
  __builtin_amdgcn_global_load_lds(
      (const __attribute__((address_space(1))) unsigned int*)g,
      (__attribute__((address_space(3))) unsigned int*)l, 16, 0, 0);
}
DEVFN f32x4 mfma16(u16x8 a, u16x8 b, f32x4 c) {
  return __builtin_amdgcn_mfma_f32_16x16x32_bf16(
      __builtin_bit_cast(bf16x8, a), __builtin_bit_cast(bf16x8, b), c, 0, 0, 0);
}
// compiler-invisible LDS read; waits are manual (counted lgkmcnt)
DEVFN u16x8 lds_rd128(unsigned addr) {
  u16x8 r;
  asm volatile("ds_read_b128 %0, %1" : "=v"(r) : "v"(addr));
  return r;
}
DEVFN unsigned lds_addr(const void* p) {
  return (unsigned)(unsigned long)(const __attribute__((address_space(3))) char*)p;
}

#define EPI_BIAS 1
#define EPI_ACCUM 2
#define EPI_GELU 4
#define EPI_RSCALE 16
#define EPI_OUTBF 8

// ================= gemmsq: 128x128, 4 waves (2x2), wave-tile 64x64, BK=64 =================
// Same R6 skeleton (2 LDS bufs, swizzle, counted vmcnt(8)/lgkmcnt, setprio) but square
// wave tiles: per-tile LDS 128->96 KB (A-frag duplication 4x->2x). A/B vs gemm128.
template <int EPI>
__global__ __launch_bounds__(256, 2) void gemmsq_k(
    const unsigned short* __restrict__ A, const unsigned short* __restrict__ Bt,
    const float* __restrict__ bias, void* __restrict__ C,
    int Mr, int Nr, int Kr, int lda, int ldb, int ldc) {
  __shared__ unsigned short smA[2][128 * 64];
  __shared__ unsigned short smB[2][128 * 64];

  int tid = threadIdx.x, wv = tid >> 6, ll = tid & 63;
  int wm = wv >> 1, wn = wv & 1;  // 2 x 2 wave grid; wave-tile 64x64
  int m0 = blockIdx.x * 128, n0 = blockIdx.y * 128;
  int fr = ll & 15, f16 = ll >> 4, fk = f16 * 8;

  const char* Ab = (const char*)A;
  const char* Bb = (const char*)Bt;

  // staging source byte offsets (inverse-swizzled); layout [kh half-K][row][64B]
  unsigned int offA[4], offB[4];
#pragma unroll
  for (int ro = 0; ro < 4; ro++) {
    int L = (ro * 256 + tid) * 16;  // < 16384
    int P = L ^ (((L >> 9) & 1) << 5);
    int kh = P >> 13, rem = P & 8191;
    int r = rem >> 6, cb = rem & 63;
    long rowA = min(m0 + r, Mr - 1);
    offA[ro] = (unsigned)((rowA * lda + kh * 32) * 2 + cb);
    long rowB = min(n0 + r, Nr - 1);
    offB[ro] = (unsigned)((rowB * ldb + kh * 32) * 2 + cb);
  }
  // fragment LDS byte addresses (buf0, kh0), swizzled
  unsigned aAb = lds_addr(&smA[0][0]), aBb = lds_addr(&smB[0][0]);
  unsigned offArd[4], offBrd[4];
#pragma unroll
  for (int i = 0; i < 4; i++) {
    int r = wm * 64 + i * 16 + fr;
    offArd[i] = aAb + (unsigned)(r * 64 + 2 * (fk ^ (((r >> 3) & 1) << 4)));
  }
#pragma unroll
  for (int j = 0; j < 4; j++) {
    int r = wn * 64 + j * 16 + fr;
    offBrd[j] = aBb + (unsigned)(r * 64 + 2 * (fk ^ (((r >> 3) & 1) << 4)));
  }

  f32x4 acc[4][4] = {};
  int NT = Kr / 64;  // even for all our shapes

#define STGALL(PB, KBN)                                                      \
  {                                                                          \
    _Pragma("unroll") for (int ro = 0; ro < 4; ro++)                         \
        gl_lds16(Ab + offA[ro] + (KBN), &smA[PB][(ro * 256 + wv * 64) * 8]); \
    _Pragma("unroll") for (int ro = 0; ro < 4; ro++)                         \
        gl_lds16(Bb + offB[ro] + (KBN), &smB[PB][(ro * 256 + wv * 64) * 8]); \
  }
#define KSBODY(PB, KS)                                                       \
  {                                                                          \
    u16x8 a[4], b[4];                                                        \
    _Pragma("unroll") for (int i = 0; i < 4; i++)                            \
        a[i] = lds_rd128(offArd[i] + (PB)*16384 + (KS)*8192);                \
    _Pragma("unroll") for (int j = 0; j < 4; j++)                            \
        b[j] = lds_rd128(offBrd[j] + (PB)*16384 + (KS)*8192);                \
    asm volatile("s_waitcnt lgkmcnt(2)" ::: "memory");                       \
    __builtin_amdgcn_sched_barrier(0);                                       \
    __builtin_amdgcn_s_setprio(1);                                           \
    _Pragma("unroll") for (int i = 0; i < 4; i++) {                          \
      acc[i][0] = mfma16(a[i], b[0], acc[i][0]);                             \
      acc[i][1] = mfma16(a[i], b[1], acc[i][1]);                             \
    }                                                                        \
    __builtin_amdgcn_s_setprio(0);                                           \
    asm volatile("s_waitcnt lgkmcnt(0)" ::: "memory");                       \
    __builtin_amdgcn_sched_barrier(0);                                       \
    __builtin_amdgcn_s_setprio(1);                                           \
    _Pragma("unroll") for (int i = 0; i < 4; i++) {                          \
      acc[i][2] = mfma16(a[i], b[2], acc[i][2]);                             \
      acc[i][3] = mfma16(a[i], b[3], acc[i][3]);                             \
    }                                                                        \
    __builtin_amdgcn_s_setprio(0);                                           \
  }
#define TILE(PB, KBN)                                                        \
  {                                                                          \
    __builtin_amdgcn_s_barrier();                                            \
    __builtin_amdgcn_sched_barrier(0);                                       \
    STGALL((PB) ^ 1, KBN);                                                   \
    asm volatile("s_waitcnt vmcnt(8)" ::: "memory");                         \
    __builtin_amdgcn_sched_barrier(0);                                       \
    __builtin_amdgcn_s_barrier();                                            \
    __builtin_amdgcn_sched_barrier(0);                                       \
    KSBODY(PB, 0);                                                           \
    KSBODY(PB, 1);                                                           \
  }

  STGALL(0, 0);  // prologue: tile 0 -> buf0
  for (int t = 0; t < NT; t += 2) {
    long kb1 = (long)(t + 1) * 128;
    long kb2 = (long)min(t + 2, NT - 1) * 128;
    TILE(0, kb1);
    TILE(1, kb2);
  }
  asm volatile("s_waitcnt vmcnt(0)" ::: "memory");  // drain dangling DMA
  __builtin_amdgcn_sched_barrier(0);
#undef TILE
#undef KSBODY
#undef STGALL

  // ---- epilogue ----
#pragma unroll
  for (int i = 0; i < 4; i++) {
#pragma unroll
    for (int j = 0; j < 4; j++) {
#pragma unroll
      for (int e = 0; e < 4; e++) {
        int gr = m0 + wm * 64 + i * 16 + f16 * 4 + e;
        int gc = n0 + wn * 64 + j * 16 + fr;
        if (gr < Mr && gc < Nr) {
          float v = acc[i][j][e];
          if (EPI & EPI_BIAS) v += bias[gc];
          if (EPI & EPI_GELU) v = 0.5f * v * (1.0f + erff(v * 0.70710678118f));
          long idx = (long)gr * ldc + gc;
          if (EPI & EPI_ACCUM) v += ((float*)C)[idx];
          if (EPI & EPI_OUTBF) ((unsigned short*)C)[idx] = f2bu(v);
          else ((float*)C)[idx] = v;
        }
      }
    }
  }
}

// ================= 128x128 big GEMM (R6 best: kept for A/B + other shapes) =================
template <int EPI>
__global__ __launch_bounds__(512, 4) void gemm128_k(
    const unsigned short* __restrict__ A, const unsigned short* __restrict__ Bt,
    const float* __restrict__ bias, void* __restrict__ C,
    int Mr, int Nr, int Kr, int lda, int ldb, int ldc) {
  __shared__ unsigned short smA[2][128 * 64];
  __shared__ unsigned short smB[2][128 * 64];

  int tid = threadIdx.x, wv = tid >> 6, ll = tid & 63;
  int wm = wv >> 2, wn = wv & 3;  // 2 x 4 wave grid; per-wave out 64x32
  int m0 = blockIdx.x * 128, n0 = blockIdx.y * 128;
  int fr = ll & 15, f16 = ll >> 4, fk = f16 * 8;

  const char* Ab = (const char*)A;
  const char* Bb = (const char*)Bt;

  unsigned int offA[2], offB[2];
#pragma unroll
  for (int ro = 0; ro < 2; ro++) {
    int L = (ro * 512 + tid) * 16;
    int P = L ^ (((L >> 9) & 1) << 5);
    int kh = P >> 13, rem = P & 8191;
    int r = rem >> 6, cb = rem & 63;
    long rowA = min(m0 + r, Mr - 1);
    offA[ro] = (unsigned)((rowA * lda + kh * 32) * 2 + cb);
    long rowB = min(n0 + r, Nr - 1);
    offB[ro] = (unsigned)((rowB * ldb + kh * 32) * 2 + cb);
  }
  unsigned aAb = lds_addr(&smA[0][0]), aBb = lds_addr(&smB[0][0]);
  unsigned offArd[4], offBrd[2];
#pragma unroll
  for (int i = 0; i < 4; i++) {
    int r = wm * 64 + i * 16 + fr;
    offArd[i] = aAb + (unsigned)(r * 64 + 2 * (fk ^ (((r >> 3) & 1) << 4)));
  }
#pragma unroll
  for (int j = 0; j < 2; j++) {
    int r = wn * 32 + j * 16 + fr;
    offBrd[j] = aBb + (unsigned)(r * 64 + 2 * (fk ^ (((r >> 3) & 1) << 4)));
  }

  f32x4 acc[4][2] = {};
  int NT = Kr / 64;

#define STGALL(PB, KBN)                                                      \
  {                                                                          \
    _Pragma("unroll") for (int ro = 0; ro < 2; ro++)                         \
        gl_lds16(Ab + offA[ro] + (KBN), &smA[PB][(ro * 512 + wv * 64) * 8]); \
    _Pragma("unroll") for (int ro = 0; ro < 2; ro++)                         \
        gl_lds16(Bb + offB[ro] + (KBN), &smB[PB][(ro * 512 + wv * 64) * 8]); \
  }
#define TILE(PB, KBN)                                                        \
  {                                                                          \
    __builtin_amdgcn_s_barrier();                                            \
    __builtin_amdgcn_sched_barrier(0);                                       \
    STGALL((PB) ^ 1, KBN);                                                   \
    asm volatile("s_waitcnt vmcnt(4)" ::: "memory");                         \
    __builtin_amdgcn_sched_barrier(0);                                       \
    __builtin_amdgcn_s_barrier();                                            \
    __builtin_amdgcn_sched_barrier(0);                                       \
    u16x8 a0[4], b0[2], a1[4], b1[2];                                        \
    _Pragma("unroll") for (int i = 0; i < 4; i++)                            \
        a0[i] = lds_rd128(offArd[i] + (PB)*16384);                           \
    _Pragma("unroll") for (int j = 0; j < 2; j++)                            \
        b0[j] = lds_rd128(offBrd[j] + (PB)*16384);                           \
    _Pragma("unroll") for (int i = 0; i < 4; i++)                            \
        a1[i] = lds_rd128(offArd[i] + (PB)*16384 + 8192);                    \
    _Pragma("unroll") for (int j = 0; j < 2; j++)                            \
        b1[j] = lds_rd128(offBrd[j] + (PB)*16384 + 8192);                    \
    asm volatile("s_waitcnt lgkmcnt(6)" ::: "memory");                       \
    __builtin_amdgcn_sched_barrier(0);                                       \
    __builtin_amdgcn_s_setprio(1);                                           \
    _Pragma("unroll") for (int i = 0; i < 4; i++) {                          \
      acc[i][0] = mfma16(a0[i], b0[0], acc[i][0]);                           \
      acc[i][1] = mfma16(a0[i], b0[1], acc[i][1]);                           \
    }                                                                        \
    __builtin_amdgcn_s_setprio(0);                                           \
    asm volatile("s_waitcnt lgkmcnt(0)" ::: "memory");                       \
    __builtin_amdgcn_sched_barrier(0);                                       \
    __builtin_amdgcn_s_setprio(1);                                           \
    _Pragma("unroll") for (int i = 0; i < 4; i++) {                          \
      acc[i][0] = mfma16(a1[i], b1[0], acc[i][0]);                           \
      acc[i][1] = mfma16(a1[i], b1[1], acc[i][1]);                           \
    }                                                                        \
    __builtin_amdgcn_s_setprio(0);                                           \
  }

  STGALL(0, 0);
  for (int t = 0; t < NT; t += 2) {
    long kb1 = (long)(t + 1) * 128;
    long kb2 = (long)min(t + 2, NT - 1) * 128;
    TILE(0, kb1);
    TILE(1, kb2);
  }
  asm volatile("s_waitcnt vmcnt(0)" ::: "memory");
  __builtin_amdgcn_sched_barrier(0);
#undef TILE
#undef STGALL

#pragma unroll
  for (int i = 0; i < 4; i++) {
#pragma unroll
    for (int j = 0; j < 2; j++) {
#pragma unroll
      for (int e = 0; e < 4; e++) {
        int gr = m0 + wm * 64 + i * 16 + f16 * 4 + e;
        int gc = n0 + wn * 32 + j * 16 + fr;
        if (gr < Mr && gc < Nr) {
          float v = acc[i][j][e];
          if (EPI & EPI_BIAS) v += bias[gc];
          if (EPI & EPI_GELU) v = 0.5f * v * (1.0f + erff(v * 0.70710678118f));
          long idx = (long)gr * ldc + gc;
          if (EPI & EPI_ACCUM) v += ((float*)C)[idx];
          if (EPI & EPI_OUTBF) ((unsigned short*)C)[idx] = f2bu(v);
          else ((float*)C)[idx] = v;
        }
      }
    }
  }
}

// ================= legacy batched GEMM, shape-templated tile MB x NB =================
template <int EPI, int MB, int NB>
__global__ __launch_bounds__(256) void gemm_k(
    const unsigned short* __restrict__ Aall, const unsigned short* __restrict__ Btall,
    const float* __restrict__ bias, void* __restrict__ Call, const float* __restrict__ rsall,
    int Mr, int Nr, int Kr, int lda, int ldb, int ldc, int bdiv,
    long As1, long As2, long Bs1, long Bs2, long Cs1, long Cs2, long Rs1, long Rs2) {
  __shared__ unsigned short smA[MB * 32];
  __shared__ unsigned short smB[NB * 32];
  constexpr int WRN = (MB == 128 && NB == 128) ? 2 : (MB == 128 ? 4 : 1);
  constexpr int WCN = 4 / WRN;
  constexpr int MT = MB / WRN, NTW = NB / WCN;
  constexpr int AF = MT / 16, BF = NTW / 16;
  int bz = blockIdx.z;
  const unsigned short* A = Aall + (long)(bz / bdiv) * As1 + (long)(bz % bdiv) * As2;
  const unsigned short* Bt = Btall + (long)(bz / bdiv) * Bs1 + (long)(bz % bdiv) * Bs2;
  long coff = (long)(bz / bdiv) * Cs1 + (long)(bz % bdiv) * Cs2;
  const float* rs = nullptr;
  if (EPI & EPI_RSCALE) rs = rsall + (long)(bz / bdiv) * Rs1 + (long)(bz % bdiv) * Rs2;

  int tid = threadIdx.x, wv = tid >> 6, ll = tid & 63;
  int m0 = blockIdx.x * MB, n0 = blockIdx.y * NB;
  int sr = tid >> 2, sc = (tid & 3) * 8;
  long ar0 = min(m0 + sr, Mr - 1);
  long ar1 = (MB == 128) ? min(m0 + sr + 64, (long)Mr - 1) : 0;
  long br0 = min(n0 + sr, Nr - 1);
  long br1 = (NB == 128) ? min(n0 + sr + 64, (long)Nr - 1) : 0;
  unsigned short* lA0 = &smA[(wv * 16) * 32];
  unsigned short* lA1 = &smA[(64 + wv * 16) * 32];
  unsigned short* lB0 = &smB[(wv * 16) * 32];
  unsigned short* lB1 = &smB[(64 + wv * 16) * 32];

  f32x4 acc[AF][BF] = {};
  int wr = (WRN == 1) ? 0 : ((WRN == 2) ? (wv >> 1) * MT : wv * MT);
  int wc = (WCN == 1) ? 0 : ((WCN == 2) ? (wv & 1) * NTW : wv * NTW);
  int fr = ll & 15, fk = (ll >> 4) * 8;

  for (int k0 = 0; k0 < Kr; k0 += 32) {
    __syncthreads();
    gl_lds16(A + ar0 * lda + k0 + sc, lA0);
    if (MB == 128) gl_lds16(A + ar1 * lda + k0 + sc, lA1);
    gl_lds16(Bt + br0 * ldb + k0 + sc, lB0);
    if (NB == 128) gl_lds16(Bt + br1 * ldb + k0 + sc, lB1);
    __syncthreads();
    u16x8 af[AF], bfr[BF];
#pragma unroll
    for (int i = 0; i < AF; i++) af[i] = *(const u16x8*)&smA[(wr + i * 16 + fr) * 32 + fk];
#pragma unroll
    for (int j = 0; j < BF; j++) bfr[j] = *(const u16x8*)&smB[(wc + j * 16 + fr) * 32 + fk];
#pragma unroll
    for (int i = 0; i < AF; i++)
#pragma unroll
      for (int j = 0; j < BF; j++) acc[i][j] = mfma16(af[i], bfr[j], acc[i][j]);
  }

#pragma unroll
  for (int i = 0; i < AF; i++) {
#pragma unroll
    for (int j = 0; j < BF; j++) {
#pragma unroll
      for (int e = 0; e < 4; e++) {
        int gr = m0 + wr + i * 16 + (ll >> 4) * 4 + e;
        int gc = n0 + wc + j * 16 + (ll & 15);
        if (gr < Mr && gc < Nr) {
          float v = acc[i][j][e];
          if (EPI & EPI_BIAS) v += bias[gc];
          if (EPI & EPI_GELU) v = 0.5f * v * (1.0f + erff(v * 0.70710678118f));
          if (EPI & EPI_RSCALE) v *= rs[gr];
          long idx = coff + (long)gr * ldc + gc;
          if (EPI & EPI_ACCUM) v += ((float*)Call)[idx];
          if (EPI & EPI_OUTBF) ((unsigned short*)Call)[idx] = f2bu(v);
          else ((float*)Call)[idx] = v;
        }
      }
    }
  }
}

// ================= fused FAVOR+ kernels =================
DEVFN void feat_dd(const unsigned short* __restrict__ src, const unsigned short* __restrict__ projc,
                   unsigned short* ldsq, unsigned short* ldsp, int b, int t0, int hh,
                   f32x4 acc[16]) {
  int tid = threadIdx.x, wv = tid >> 6, ll = tid & 63;
#pragma unroll
  for (int p = 0; p < 2; p++) {
    int r = p * 64 + (tid >> 3), c8 = (tid & 7) * 8;
    *(u16x8*)&ldsq[r * 72 + c8] =
        *(const u16x8*)&src[((long)b * CT + t0 + r) * CQKV + hh * CDH + c8];
  }
#pragma unroll
  for (int p = 0; p < 4; p++) {
    int r = p * 64 + (tid >> 3), c8 = (tid & 7) * 8;
    *(u16x8*)&ldsp[r * 72 + c8] = *(const u16x8*)&projc[r * 64 + c8];
  }
  __syncthreads();
  int fr = ll & 15, fk = (ll >> 4) * 8;
#pragma unroll
  for (int ks = 0; ks < 2; ks++) {
    u16x8 af = *(const u16x8*)&ldsq[(wv * 16 + fr) * 72 + ks * 32 + fk];
#pragma unroll
    for (int j = 0; j < 16; j++) {
      u16x8 bf = *(const u16x8*)&ldsp[(j * 16 + fr) * 72 + ks * 32 + fk];
      acc[j] = mfma16(af, bf, acc[j]);
    }
  }
}

__global__ __launch_bounds__(512, 4) void kstab_f(const unsigned short* __restrict__ kb,
                                                  const unsigned short* __restrict__ projc,
                                                  float* __restrict__ part) {
  extern __shared__ char dynsm[];
  unsigned short* ldsq = (unsigned short*)dynsm;            // [128][72]
  unsigned short* ldsp = (unsigned short*)(dynsm + 18432);  // [256][72]
  __shared__ float smx[8];
  int bh = blockIdx.x >> 3, chunk = blockIdx.x & 7;
  int b = bh >> 4, hh = bh & 15;
  f32x4 acc[16] = {};
  feat_dd(kb, projc, ldsq, ldsp, b, chunk * 128, hh, acc);
  float mx = -3.4e38f;
#pragma unroll
  for (int j = 0; j < 16; j++)
#pragma unroll
    for (int e = 0; e < 4; e++) mx = fmaxf(mx, acc[j][e]);
  mx = wredmax(mx);
  int wv = threadIdx.x >> 6;
  if ((threadIdx.x & 63) == 0) smx[wv] = mx;
  __syncthreads();
  if (threadIdx.x == 0) {
    float m2 = smx[0];
#pragma unroll
    for (int i = 1; i < 8; i++) m2 = fmaxf(m2, smx[i]);
    part[blockIdx.x] = m2;
  }
}

__global__ __launch_bounds__(512, 4) void featk_f(const unsigned short* __restrict__ kb,
                                                  const unsigned short* __restrict__ projc,
                                                  const float* __restrict__ part,
                                                  unsigned short* __restrict__ kpt,
                                                  float* __restrict__ kspart) {
  extern __shared__ char dynsm[];
  unsigned short* ldsq = (unsigned short*)dynsm;            // [128][72]
  unsigned short* ldsp = (unsigned short*)(dynsm + 18432);  // [256][72]
  unsigned short* ldso = (unsigned short*)dynsm;            // overlay [256][136]
  int tid = threadIdx.x, wv = tid >> 6, ll = tid & 63;
  int bh = blockIdx.x >> 3, chunk = blockIdx.x & 7;
  int b = bh >> 4, hh = bh & 15;
  float st = part[bh * 8];
#pragma unroll
  for (int i = 1; i < 8; i++) st = fmaxf(st, part[bh * 8 + i]);
  f32x4 acc[16] = {};
  feat_dd(kb, projc, ldsq, ldsp, b, chunk * 128, hh, acc);
  int fr = ll & 15, g = ll >> 4;
  float diag[4];
#pragma unroll
  for (int e = 0; e < 4; e++) {
    int row = wv * 16 + g * 4 + e;
    u16x4 kv = *(const u16x4*)&ldsq[row * 72 + fr * 4];
    float s = 0;
#pragma unroll
    for (int z = 0; z < 4; z++) { float f = b2f(kv[z]); s += f * f; }
#pragma unroll
    for (int o = 1; o < 16; o <<= 1) s += __shfl_xor(s, o, 64);
    diag[e] = s * (0.5f * CDN * CDN);
  }
  __syncthreads();
#pragma unroll
  for (int j = 0; j < 16; j++)
#pragma unroll
    for (int e = 0; e < 4; e++) {
      float v = CRATIO * (expf(acc[j][e] - diag[e] - st) + CKEPS);
      ldso[(j * 16 + fr) * 136 + wv * 16 + g * 4 + e] = f2bu(v);
    }
  __syncthreads();
  int m = tid >> 1, seg = (tid & 1) * 64;
  long base = ((long)bh * CM + m) * CT + chunk * 128;
  float ks = 0;
#pragma unroll
  for (int z = 0; z < 8; z++) {
    u16x8 v8 = *(u16x8*)&ldso[m * 136 + seg + z * 8];
    *(u16x8*)&kpt[base + seg + z * 8] = v8;
#pragma unroll
    for (int w = 0; w < 8; w++) ks += b2f(v8[w]);
  }
  ks += __shfl_xor(ks, 1, 64);
  if ((tid & 1) == 0) kspart[((long)bh * 8 + chunk) * CM + m] = ks;
}

__global__ __launch_bounds__(256) void ksred_k(const float* __restrict__ kspart,
                                               float* __restrict__ ksum) {
  int i = blockIdx.x * 256 + threadIdx.x;  // < 32768
  int bh = i >> 8, m = i & 255;
  float s = 0;
#pragma unroll
  for (int c = 0; c < 8; c++) s += kspart[((long)bh * 8 + c) * CM + m];
  ksum[i] = s;
}

__global__ __launch_bounds__(512, 4) void featq_f(const unsigned short* __restrict__ qb,
                                                  const unsigned short* __restrict__ projc,
                                                  const float* __restrict__ ksum,
                                                  unsigned short* __restrict__ qp,
                                                  float* __restrict__ dinv) {
  extern __shared__ char dynsm[];
  unsigned short* ldsq = (unsigned short*)dynsm;            // [128][72]
  unsigned short* ldsp = (unsigned short*)(dynsm + 18432);  // [256][72]
  unsigned short* ldso = (unsigned short*)dynsm;            // overlay [128][264]
  float* ldks = (float*)(dynsm + 67584);                    // [256]
  int tid = threadIdx.x, wv = tid >> 6, ll = tid & 63;
  int bh = blockIdx.x >> 3, chunk = blockIdx.x & 7;
  int b = bh >> 4, hh = bh & 15;
  int t0 = chunk * 128;
  if (tid < 256) ldks[tid] = ksum[bh * CM + tid];
  f32x4 acc[16] = {};
  feat_dd(qb, projc, ldsq, ldsp, b, t0, hh, acc);
  int fr = ll & 15, g = ll >> 4;
  float rmax[4], diag[4];
#pragma unroll
  for (int e = 0; e < 4; e++) {
    float mx = acc[0][e];
#pragma unroll
    for (int j = 1; j < 16; j++) mx = fmaxf(mx, acc[j][e]);
#pragma unroll
    for (int o = 1; o < 16; o <<= 1) mx = fmaxf(mx, __shfl_xor(mx, o, 64));
    rmax[e] = mx;
    int row = wv * 16 + g * 4 + e;
    u16x4 qv = *(const u16x4*)&ldsq[row * 72 + fr * 4];
    float s = 0;
#pragma unroll
    for (int z = 0; z < 4; z++) { float f = b2f(qv[z]); s += f * f; }
#pragma unroll
    for (int o = 1; o < 16; o <<= 1) s += __shfl_xor(s, o, 64);
    diag[e] = s * (0.5f * CDN * CDN);
  }
  __syncthreads();
#pragma unroll
  for (int j = 0; j < 16; j++)
#pragma unroll
    for (int e = 0; e < 4; e++) {
      float v = CRATIO * (expf(acc[j][e] - diag[e] - rmax[e]) + CKEPS);
      ldso[(wv * 16 + g * 4 + e) * 264 + j * 16 + fr] = f2bu(v);
    }
  __syncthreads();
  int row = tid >> 2, seg = (tid & 3) * 64;
  long base = ((long)bh * CT + t0) * CM;
  float dot = 0;
#pragma unroll
  for (int z = 0; z < 8; z++) {
    u16x8 v8 = *(u16x8*)&ldso[row * 264 + seg + z * 8];
    *(u16x8*)&qp[base + (long)row * CM + seg + z * 8] = v8;
#pragma unroll
    for (int w = 0; w < 8; w++) dot += b2f(v8[w]) * ldks[seg + z * 8 + w];
  }
  dot += __shfl_xor(dot, 1, 64);
  dot += __shfl_xor(dot, 2, 64);
  if ((tid & 3) == 0) dinv[(long)bh * CT + t0 + row] = 1.0f / dot;
}

// ---------------- LayerNorm ----------------
__global__ __launch_bounds__(256) void ln_k(const float* __restrict__ h,
                                            const float* __restrict__ g,
                                            const float* __restrict__ b,
                                            unsigned short* __restrict__ y) {
  int wv = threadIdx.x >> 6, ll = threadIdx.x & 63;
  long row = (long)blockIdx.x * 4 + wv;
  const float* hr = h + row * CDM;
  f32x4 x[4];
#pragma unroll
  for (int i = 0; i < 4; i++) x[i] = *(const f32x4*)&hr[ll * 16 + i * 4];
  float s = 0;
#pragma unroll
  for (int i = 0; i < 4; i++)
#pragma unroll
    for (int e = 0; e < 4; e++) s += x[i][e];
  float mu = wredsum(s) * (1.f / CDM);
  float v = 0;
#pragma unroll
  for (int i = 0; i < 4; i++)
#pragma unroll
    for (int e = 0; e < 4; e++) {
      float d = x[i][e] - mu;
      v += d * d;
    }
  float inv = rsqrtf(wredsum(v) * (1.f / CDM) + 1e-5f);
  unsigned short o[16];
#pragma unroll
  for (int i = 0; i < 4; i++)
#pragma unroll
    for (int e = 0; e < 4; e++) {
      int c = ll * 16 + i * 4 + e;
      o[i * 4 + e] = f2bu((x[i][e] - mu) * inv * g[c] + b[c]);
    }
  *(u16x8*)&y[row * CDM + ll * 16] = *(u16x8*)&o[0];
  *(u16x8*)&y[row * CDM + ll * 16 + 8] = *(u16x8*)&o[8];
}

// ---------------- v -> v_t ----------------
__global__ __launch_bounds__(256) void trv_k(const unsigned short* __restrict__ vb,
                                             unsigned short* __restrict__ vt) {
  int bh = blockIdx.x >> 5;
  int t0 = (blockIdx.x & 31) * 32;
  int b = bh >> 4, hh = bh & 15;
  __shared__ unsigned short tile[32][64];
  int tr = threadIdx.x >> 3, dblk = (threadIdx.x & 7) * 8;
  *(u16x8*)&tile[tr][dblk] = *(const u16x8*)&vb[((long)b * CT + t0 + tr) * CQKV + hh * CDH + dblk];
  __syncthreads();
  int d = threadIdx.x >> 2, tz = (threadIdx.x & 3) * 8;
  unsigned short o[8];
#pragma unroll
  for (int e = 0; e < 8; e++) o[e] = tile[tz + e][d];
  *(u16x8*)&vt[((long)bh * CDH + d) * CT + t0 + tz] = *(u16x8*)&o[0];
}

// ---------------- h += pe ----------------
__global__ __launch_bounds__(256) void addpe_k(float* __restrict__ h, const float* __restrict__ pe) {
  long i = ((long)blockIdx.x * 256 + threadIdx.x) * 4;
  int t = (int)((i >> 10) & 1023);
  int c = (int)(i & 1023);
  f32x4 v = *(f32x4*)&h[i];
  f32x4 p = *(const f32x4*)&pe[(long)t * 1024 + c];
  v += p;
  *(f32x4*)&h[i] = v;
}

// ---------------- fp32 -> bf16 flat ----------------
__global__ __launch_bounds__(256) void f2b_k(const float* __restrict__ in,
                                             unsigned short* __restrict__ out, long n) {
  long i = ((long)blockIdx.x * 256 + threadIdx.x) * 4;
  if (i >= n) return;
  f32x4 v = *(const f32x4*)&in[i];
  unsigned short o[4];
#pragma unroll
  for (int e = 0; e < 4; e++) o[e] = f2bu(v[e]);
  *(u16x4*)&out[i] = *(u16x4*)&o[0];
}

// ---------------- z-batched transpose-convert: (R,C) fp32 -> (C,R) bf16 ----------------
__global__ __launch_bounds__(256) void tconvz_k(const float* __restrict__ in,
                                                unsigned short* __restrict__ out, int R, int C,
                                                long szs, long dzs) {
  const float* src = in + (long)blockIdx.z * szs;
  unsigned short* dst = out + (long)blockIdx.z * dzs;
  __shared__ float tile[32][33];
  int r0 = blockIdx.x * 32, c0 = blockIdx.y * 32;
  int tr = threadIdx.x >> 5, tc = threadIdx.x & 31;
#pragma unroll
  for (int p = 0; p < 4; p++) {
    int r = r0 + p * 8 + tr, c = c0 + tc;
    tile[p * 8 + tr][tc] = (r < R && c < C) ? src[(long)r * C + c] : 0.f;
  }
  __syncthreads();
#pragma unroll
  for (int p = 0; p < 4; p++) {
    int c = c0 + p * 8 + tr, r = r0 + tc;
    if (c < C && r < R) dst[(long)c * R + r] = f2bu(tile[tc][p * 8 + tr]);
  }
}

// ---------------- Wconv -> per-tap bf16 ----------------
__global__ __launch_bounds__(256) void wconv_k(const float* __restrict__ W,
                                               unsigned short* __restrict__ out) {
  int idx = blockIdx.x * 256 + threadIdx.x;
  int r = idx >> 16, rem = idx & 65535, oc = rem >> 10, ic = rem & 1023;
  out[idx] = f2bu(W[oc * 3072 + ic * 3 + r]);
}

// ---------------- conv tap-mix ----------------
__global__ __launch_bounds__(256) void convmix_k(const float* __restrict__ Y,
                                                 const float* __restrict__ bc,
                                                 float* __restrict__ xa) {
  long t = (long)blockIdx.x * 4 + (threadIdx.x >> 6);
  int oc = threadIdx.x & 63;
  long tm = t > 0 ? t - 1 : 0, tp = t < CNT - 1 ? t + 1 : CNT - 1;
  float v = Y[tm * 192 + oc] + Y[t * 192 + 64 + oc] + Y[tp * 192 + 128 + oc] + bc[oc];
  xa[t * 64 + oc] = v;
}

// ---------------- proj * dn -> bf16 ----------------
__global__ __launch_bounds__(256) void projc_k(const float* __restrict__ p,
                                               unsigned short* __restrict__ out) {
  int i = blockIdx.x * 256 + threadIdx.x;
  out[i] = f2bu(p[i] * CDN);
}

// ---------------- concat q/k/v biases (z = layer) ----------------
__global__ __launch_bounds__(256) void catb_k(const float* __restrict__ q,
                                              const float* __restrict__ k,
                                              const float* __restrict__ v,
                                              float* __restrict__ o) {
  int l = blockIdx.y;
  int i = blockIdx.x * 256 + threadIdx.x;  // < 3072
  float val = i < 1024 ? q[l * CDM + i] : (i < 2048 ? k[l * CDM + i - 1024] : v[l * CDM + i - 2048]);
  o[l * CQKV + i] = val;
}

// ---------------- exact conv recompute at batch boundaries ----------------
__global__ __launch_bounds__(256) void patch_k(const float* __restrict__ h,
                                               const float* __restrict__ W,
                                               const float* __restrict__ bc,
                                               float* __restrict__ xa) {
  int b = blockIdx.x >> 1;
  int t = (blockIdx.x & 1) ? (CT - 1) : 0;
  int oc = threadIdx.x & 63, ch = threadIdx.x >> 6;
  float s = 0;
  for (int r = 0; r < 3; r++) {
    int tt = t + r - 1;
    if (tt < 0 || tt >= CT) continue;
    const float* hr = h + ((long)b * CT + tt) * CDM;
    const float* wr = W + oc * 3072 + r;
    for (int ic = ch * 256; ic < ch * 256 + 256; ic++) s += hr[ic] * wr[ic * 3];
  }
  __shared__ float sm[256];
  sm[threadIdx.x] = s;
  __syncthreads();
  if (threadIdx.x < 64) {
    float tot = sm[oc] + sm[64 + oc] + sm[128 + oc] + sm[192 + oc] + bc[oc];
    xa[((long)b * CT + t) * 64 + oc] = tot;
  }
}

#define LAUNCH_GEMM(EPI, MB, NB, A, Bt, bias, C, rsp, Mr, Nr, Kr, lda, ldb, ldc, nb, bdiv, As1, As2, Bs1, Bs2, Cs1, Cs2, Rs1, Rs2) \
  gemm_k<EPI, MB, NB><<<dim3(((Mr) + (MB)-1) / (MB), ((Nr) + (NB)-1) / (NB), (nb)), 256, 0, stream>>>( \
      (const unsigned short*)(A), (const unsigned short*)(Bt), (bias), (void*)(C), (rsp),        \
      (Mr), (Nr), (Kr), (lda), (ldb), (ldc), (bdiv), (long)(As1), (long)(As2), (long)(Bs1),      \
      (long)(Bs2), (long)(Cs1), (long)(Cs2), (long)(Rs1), (long)(Rs2))

#define LAUNCH_G1(EPI, A, Bt, bias, C, Mr, Nr, Kr, lda, ldb, ldc)                                \
  gemm128_k<EPI><<<dim3(((Mr) + 127) / 128, ((Nr) + 127) / 128), 512, 0, stream>>>(              \
      (const unsigned short*)(A), (const unsigned short*)(Bt), (bias), (void*)(C),               \
      (Mr), (Nr), (Kr), (lda), (ldb), (ldc))

#define LAUNCH_GS(EPI, A, Bt, bias, C, Mr, Nr, Kr, lda, ldb, ldc)                                \
  gemmsq_k<EPI><<<dim3(((Mr) + 127) / 128, ((Nr) + 127) / 128), 256, 0, stream>>>(               \
      (const unsigned short*)(A), (const unsigned short*)(Bt), (bias), (void*)(C),               \
      (Mr), (Nr), (Kr), (lda), (ldb), (ldc))

extern "C" void kernel_launch(void* const* d_in, const int* in_sizes, int n_in,
                              void* d_out, int out_size, void* d_ws, size_t ws_size,
                              hipStream_t stream) {
  const float* x = (const float*)d_in[0];
  const float* Win = (const float*)d_in[1];
  const float* b_in = (const float*)d_in[2];
  const float* pe = (const float*)d_in[3];
  const float* ln1_g = (const float*)d_in[4];
  const float* ln1_b = (const float*)d_in[5];
  const float* Wq = (const float*)d_in[6];
  const float* bq = (const float*)d_in[7];
  const float* Wk = (const float*)d_in[8];
  const float* bk = (const float*)d_in[9];
  const float* Wv = (const float*)d_in[10];
  const float* bv = (const float*)d_in[11];
  const float* Wo = (const float*)d_in[12];
  const float* bo = (const float*)d_in[13];
  const float* ln2_g = (const float*)d_in[14];
  const float* ln2_b = (const float*)d_in[15];
  const float* W1 = (const float*)d_in[16];
  const float* b1 = (const float*)d_in[17];
  const float* W2 = (const float*)d_in[18];
  const float* b2 = (const float*)d_in[19];
  const float* Wc = (const float*)d_in[20];
  const float* bc = (const float*)d_in[21];
  const float* Wconv = (const float*)d_in[22];
  const float* bconv = (const float*)d_in[23];
  const float* Waux = (const float*)d_in[24];
  const float* baux = (const float*)d_in[25];
  const float* proj = (const float*)d_in[26];
  float* out = (float*)d_out;

  char* wsp = (char*)d_ws;
  size_t off = 0;
  auto take = [&](size_t bytes) {
    char* p = wsp + off;
    off = (off + bytes + 255) & ~(size_t)255;
    return p;
  };
  float* h_f = (float*)take(33554432);                      // (8192,1024) fp32 residual
  unsigned short* y_bf = (unsigned short*)take(16777216);   // LN out; aliased: vt, o
  unsigned short* qkv_bf = (unsigned short*)take(50331648); // (8192,3072) fused q,k,v
  unsigned short* qp_bf = (unsigned short*)take(67108864);  // (B,H,T,M)
  unsigned short* kpt_bf = (unsigned short*)take(67108864); // (B,H,M,T)
  unsigned short* ff_bf = (unsigned short*)take(67108864);  // (8192,4096) FFN mid
  unsigned short* ctx_bf = (unsigned short*)take(4194304);  // (B,H,DH,M)
  float* ksum_f = (float*)take(131072);
  float* kspart_f = (float*)take(1048576);                  // (bh,8,256)
  float* kstab_f_buf = (float*)take(4096);                  // (bh,8)
  float* dinv_f = (float*)take(524288);
  float* xa_f = (float*)take(2097152);
  float* ycv_f = (float*)take(6291456);                     // (8192,192) conv taps
  unsigned short* xabf = (unsigned short*)take(1048576);
  float* bqkv_f = (float*)take(24576);                      // 2 layers x 3072
  unsigned short* hbf = (unsigned short*)take(16777216);
  unsigned short* xbf = (unsigned short*)take(4194304);
  unsigned short* win_t = (unsigned short*)take(524288);
  unsigned short* wqkvo_t = (unsigned short*)take(16777216);
  unsigned short* w1_t = (unsigned short*)take(16777216);
  unsigned short* w2_t = (unsigned short*)take(16777216);
  unsigned short* wc_t = (unsigned short*)take(4096000);
  unsigned short* projc = (unsigned short*)take(32768);
  unsigned short* wconv_t = (unsigned short*)take(393216);
  unsigned short* waux_t = (unsigned short*)take(256128);
  unsigned short* vt_bf = y_bf;                    // alias (y dead after QKV)
  unsigned short* o_bf = y_bf;                     // alias (vt dead after ctx)
  (void)in_sizes; (void)n_in; (void)out_size; (void)ws_size;

  // ---- weight conversion (z-batched; 13 launches) ----
  f2b_k<<<2048, 256, 0, stream>>>(x, xbf, (long)CNT * 256);
  tconvz_k<<<dim3(8, 32, 1), 256, 0, stream>>>(Win, win_t, 256, 1024, 0, 0);
  tconvz_k<<<dim3(32, 32, 2), 256, 0, stream>>>(Wq, wqkvo_t + 0 * 1048576, 1024, 1024, 1048576, 4194304);
  tconvz_k<<<dim3(32, 32, 2), 256, 0, stream>>>(Wk, wqkvo_t + 1 * 1048576, 1024, 1024, 1048576, 4194304);
  tconvz_k<<<dim3(32, 32, 2), 256, 0, stream>>>(Wv, wqkvo_t + 2 * 1048576, 1024, 1024, 1048576, 4194304);
  tconvz_k<<<dim3(32, 32, 2), 256, 0, stream>>>(Wo, wqkvo_t + 3 * 1048576, 1024, 1024, 1048576, 4194304);
  tconvz_k<<<dim3(32, 128, 2), 256, 0, stream>>>(W1, w1_t, 1024, 4096, 4194304, 4194304);
  tconvz_k<<<dim3(128, 32, 2), 256, 0, stream>>>(W2, w2_t, 4096, 1024, 4194304, 4194304);
  tconvz_k<<<dim3(32, 63, 1), 256, 0, stream>>>(Wc, wc_t, 1024, 2000, 0, 0);
  tconvz_k<<<dim3(2, 63, 1), 256, 0, stream>>>(Waux, waux_t, 64, 2001, 0, 0);
  catb_k<<<dim3(12, 2), 256, 0, stream>>>(bq, bk, bv, bqkv_f);
  wconv_k<<<768, 256, 0, stream>>>(Wconv, wconv_t);
  projc_k<<<64, 256, 0, stream>>>(proj, projc);

  // ---- embed ----
  LAUNCH_G1(EPI_BIAS, xbf, win_t, b_in, h_f, CNT, CDM, 256, 256, 256, CDM);
  addpe_k<<<8192, 256, 0, stream>>>(h_f, pe);

  for (int l = 0; l < 2; l++) {
    const unsigned short* wqkv_t = wqkvo_t + (long)(l * 4) * 1048576;  // q,k,v adjacent
    const unsigned short* wo_t = wqkvo_t + (long)(l * 4 + 3) * 1048576;

    ln_k<<<2048, 256, 0, stream>>>(h_f, ln1_g + l * CDM, ln1_b + l * CDM, y_bf);
    // QKV on gemmsq (A/B vs gemm128 on FFN2/classifier)
    LAUNCH_GS(EPI_BIAS | EPI_OUTBF, y_bf, wqkv_t, bqkv_f + l * CQKV, qkv_bf, CNT, CQKV, CDM, CDM, CDM, CQKV);

    // fused FAVOR+: keys (2 passes) then queries (+dinv)
    kstab_f<<<1024, 512, 55296, stream>>>(qkv_bf + 1024, projc, kstab_f_buf);
    featk_f<<<1024, 512, 69632, stream>>>(qkv_bf + 1024, projc, kstab_f_buf, kpt_bf, kspart_f);
    ksred_k<<<128, 256, 0, stream>>>(kspart_f, ksum_f);
    featq_f<<<1024, 512, 68608, stream>>>(qkv_bf, projc, ksum_f, qp_bf, dinv_f);
    trv_k<<<4096, 256, 0, stream>>>(qkv_bf + 2048, vt_bf);
    // ctx^T (DH,M) = v^T @ kp, batched — 64x128 tiles
    LAUNCH_GEMM(EPI_OUTBF, 64, 128, vt_bf, kpt_bf, nullptr, ctx_bf, nullptr, CDH, CM, CT, CT, CT, CM, 128, CH,
                (long)CH * CDH * CT, (long)CDH * CT, (long)CH * CM * CT, (long)CM * CT,
                (long)CH * CDH * CM, (long)CDH * CM, 0, 0);
    // o = (qp @ ctx) * dinv — 128x64 tiles
    LAUNCH_GEMM(EPI_RSCALE | EPI_OUTBF, 128, 64, qp_bf, ctx_bf, nullptr, o_bf, dinv_f, CT, CDH, CM, CM, CM, CDM, 128, CH,
                (long)CH * CT * CM, (long)CT * CM, (long)CH * CDH * CM, (long)CDH * CM,
                (long)CT * CDM, 64, (long)CH * CT, (long)CT);
    LAUNCH_G1(EPI_BIAS | EPI_ACCUM, o_bf, wo_t, bo + l * CDM, h_f, CNT, CDM, CDM, CDM, CDM, CDM);

    ln_k<<<2048, 256, 0, stream>>>(h_f, ln2_g + l * CDM, ln2_b + l * CDM, y_bf);
    // FFN1 on gemmsq
    LAUNCH_GS(EPI_BIAS | EPI_GELU | EPI_OUTBF, y_bf, w1_t + (long)l * 4194304, b1 + l * CDFF, ff_bf,
              CNT, CDFF, CDM, CDM, CDM, CDFF);
    LAUNCH_G1(EPI_BIAS | EPI_ACCUM, ff_bf, w2_t + (long)l * 4194304, b2 + l * CDM, h_f,
              CNT, CDM, CDFF, CDFF, CDFF, CDM);

    if (l == 0) {
      f2b_k<<<8192, 256, 0, stream>>>(h_f, hbf, (long)CNT * CDM);
      LAUNCH_GEMM(0, 128, 128, hbf, wconv_t, nullptr, ycv_f, nullptr, CNT, 192, CDM, CDM, CDM, 192, 1, 1, 0, 0, 0, 0, 0, 0, 0, 0);
      convmix_k<<<2048, 256, 0, stream>>>(ycv_f, bconv, xa_f);
      patch_k<<<16, 256, 0, stream>>>(h_f, Wconv, bconv, xa_f);
      f2b_k<<<512, 256, 0, stream>>>(xa_f, xabf, (long)CNT * 64);
      LAUNCH_GEMM(EPI_BIAS, 128, 128, xabf, waux_t, baux, out + 16384000, nullptr, CNT, CV + 1, 64, 64, 64, CV + 1, 1, 1, 0, 0, 0, 0, 0, 0, 0, 0);
    }
  }

  // ---- classifier ----
  f2b_k<<<8192, 256, 0, stream>>>(h_f, hbf, (long)CNT * CDM);
  LAUNCH_G1(EPI_BIAS, hbf, wc_t, bc, out, CNT, CV, CDM, CDM, CDM, CV);
}

// Round 12
// 1213.951 us; speedup vs baseline: 1.1362x; 1.1362x over previous
//
#include <hip/hip_runtime.h>
#include <hip/hip_bf16.h>

typedef __attribute__((ext_vector_type(4))) float f32x4;
typedef __attribute__((ext_vector_type(8))) unsigned short u16x8;
typedef __attribute__((ext_vector_type(4))) unsigned short u16x4;
typedef __bf16 bf16x8 __attribute__((ext_vector_type(8)));

#define DEVFN static __device__ __forceinline__

constexpr int CB = 8, CT = 1024, CDM = 1024, CH = 16, CDH = 64, CDFF = 4096, CV = 2000, CM = 256;
constexpr int CNT = CB * CT; // 8192 tokens
constexpr int CQKV = 3072;   // fused qkv row stride
constexpr float CDN = 0.35355339059327373f;   // 64^-0.25
constexpr float CRATIO = 0.0625f;             // 256^-0.5
constexpr float CKEPS = 1e-4f;

DEVFN unsigned short f2bu(float x) {
  __hip_bfloat16 h = __float2bfloat16(x);
  return __builtin_bit_cast(unsigned short, h);
}
DEVFN float b2f(unsigned short u) {
  __hip_bfloat16 h = __builtin_bit_cast(__hip_bfloat16, u);
  return __bfloat162float(h);
}
DEVFN float wredsum(float s) {
#pragma unroll
  for (int ofs = 32; ofs; ofs >>= 1) s += __shfl_xor(s, ofs, 64);
  return s;
}
DEVFN float wredmax(float s) {
#pragma unroll
  for (int ofs = 32; ofs; ofs >>= 1) s = fmaxf(s, __shfl_xor(s, ofs, 64));
  return s;
}
DEVFN void gl_lds16(const void* g, void* l) {
  __builtin_amdgcn_global_load_lds(
      (const __attribute__((address_space(1))) unsigned int*)g,
      (__attribute__((address_space(3))) unsigned int*)l, 16, 0, 0);
}
DEVFN f32x4 mfma16(u16x8 a, u16x8 b, f32x4 c) {
  return __builtin_amdgcn_mfma_f32_16x16x32_bf16(
      __builtin_bit_cast(bf16x8, a), __builtin_bit_cast(bf16x8, b), c, 0, 0, 0);
}
// compiler-invisible LDS read; waits are manual (counted lgkmcnt)
DEVFN u16x8 lds_rd128(unsigned addr) {
  u16x8 r;
  asm volatile("ds_read_b128 %0, %1" : "=v"(r) : "v"(addr));
  return r;
}
DEVFN unsigned lds_addr(const void* p) {
  return (unsigned)(unsigned long)(const __attribute__((address_space(3))) char*)p;
}

#define EPI_BIAS 1
#define EPI_ACCUM 2
#define EPI_GELU 4
#define EPI_OUTBF 8
#define EPI_RSCALE 16
#define EPI_PE 32    // add pe[(row&1023)*1024 + col] (aux = pe fp32)
#define EPI_DUP 64   // also write bf16 copy to aux at same idx

// ================= 128x128 big GEMM (R6/R10 best measured: 122 us FFN-class) =================
// BK=64, 8 waves (2x4), 2 LDS buffers (64KB, 2 blocks/CU, 16 waves/CU), st-swizzle,
// asm ds_read + counted lgkmcnt, full-tile prefetch + counted vmcnt(4), setprio.
template <int EPI>
__global__ __launch_bounds__(512, 4) void gemm128_k(
    const unsigned short* __restrict__ A, const unsigned short* __restrict__ Bt,
    const float* __restrict__ bias, void* __restrict__ C, void* __restrict__ aux,
    int Mr, int Nr, int Kr, int lda, int ldb, int ldc) {
  __shared__ unsigned short smA[2][128 * 64];
  __shared__ unsigned short smB[2][128 * 64];

  int tid = threadIdx.x, wv = tid >> 6, ll = tid & 63;
  int wm = wv >> 2, wn = wv & 3;  // 2 x 4 wave grid; per-wave out 64x32
  int m0 = blockIdx.x * 128, n0 = blockIdx.y * 128;
  int fr = ll & 15, f16 = ll >> 4, fk = f16 * 8;

  const char* Ab = (const char*)A;
  const char* Bb = (const char*)Bt;

  unsigned int offA[2], offB[2];
#pragma unroll
  for (int ro = 0; ro < 2; ro++) {
    int L = (ro * 512 + tid) * 16;
    int P = L ^ (((L >> 9) & 1) << 5);
    int kh = P >> 13, rem = P & 8191;
    int r = rem >> 6, cb = rem & 63;
    long rowA = min(m0 + r, Mr - 1);
    offA[ro] = (unsigned)((rowA * lda + kh * 32) * 2 + cb);
    long rowB = min(n0 + r, Nr - 1);
    offB[ro] = (unsigned)((rowB * ldb + kh * 32) * 2 + cb);
  }
  unsigned aAb = lds_addr(&smA[0][0]), aBb = lds_addr(&smB[0][0]);
  unsigned offArd[4], offBrd[2];
#pragma unroll
  for (int i = 0; i < 4; i++) {
    int r = wm * 64 + i * 16 + fr;
    offArd[i] = aAb + (unsigned)(r * 64 + 2 * (fk ^ (((r >> 3) & 1) << 4)));
  }
#pragma unroll
  for (int j = 0; j < 2; j++) {
    int r = wn * 32 + j * 16 + fr;
    offBrd[j] = aBb + (unsigned)(r * 64 + 2 * (fk ^ (((r >> 3) & 1) << 4)));
  }

  f32x4 acc[4][2] = {};
  int NT = Kr / 64;

#define STGALL(PB, KBN)                                                      \
  {                                                                          \
    _Pragma("unroll") for (int ro = 0; ro < 2; ro++)                         \
        gl_lds16(Ab + offA[ro] + (KBN), &smA[PB][(ro * 512 + wv * 64) * 8]); \
    _Pragma("unroll") for (int ro = 0; ro < 2; ro++)                         \
        gl_lds16(Bb + offB[ro] + (KBN), &smB[PB][(ro * 512 + wv * 64) * 8]); \
  }
#define TILE(PB, KBN)                                                        \
  {                                                                          \
    __builtin_amdgcn_s_barrier();                                            \
    __builtin_amdgcn_sched_barrier(0);                                       \
    STGALL((PB) ^ 1, KBN);                                                   \
    asm volatile("s_waitcnt vmcnt(4)" ::: "memory");                         \
    __builtin_amdgcn_sched_barrier(0);                                       \
    __builtin_amdgcn_s_barrier();                                            \
    __builtin_amdgcn_sched_barrier(0);                                       \
    u16x8 a0[4], b0[2], a1[4], b1[2];                                        \
    _Pragma("unroll") for (int i = 0; i < 4; i++)                            \
        a0[i] = lds_rd128(offArd[i] + (PB)*16384);                           \
    _Pragma("unroll") for (int j = 0; j < 2; j++)                            \
        b0[j] = lds_rd128(offBrd[j] + (PB)*16384);                           \
    _Pragma("unroll") for (int i = 0; i < 4; i++)                            \
        a1[i] = lds_rd128(offArd[i] + (PB)*16384 + 8192);                    \
    _Pragma("unroll") for (int j = 0; j < 2; j++)                            \
        b1[j] = lds_rd128(offBrd[j] + (PB)*16384 + 8192);                    \
    asm volatile("s_waitcnt lgkmcnt(6)" ::: "memory");                       \
    __builtin_amdgcn_sched_barrier(0);                                       \
    __builtin_amdgcn_s_setprio(1);                                           \
    _Pragma("unroll") for (int i = 0; i < 4; i++) {                          \
      acc[i][0] = mfma16(a0[i], b0[0], acc[i][0]);                           \
      acc[i][1] = mfma16(a0[i], b0[1], acc[i][1]);                           \
    }                                                                        \
    __builtin_amdgcn_s_setprio(0);                                           \
    asm volatile("s_waitcnt lgkmcnt(0)" ::: "memory");                       \
    __builtin_amdgcn_sched_barrier(0);                                       \
    __builtin_amdgcn_s_setprio(1);                                           \
    _Pragma("unroll") for (int i = 0; i < 4; i++) {                          \
      acc[i][0] = mfma16(a1[i], b1[0], acc[i][0]);                           \
      acc[i][1] = mfma16(a1[i], b1[1], acc[i][1]);                           \
    }                                                                        \
    __builtin_amdgcn_s_setprio(0);                                           \
  }

  STGALL(0, 0);
  for (int t = 0; t < NT; t += 2) {
    long kb1 = (long)(t + 1) * 128;
    long kb2 = (long)min(t + 2, NT - 1) * 128;
    TILE(0, kb1);
    TILE(1, kb2);
  }
  asm volatile("s_waitcnt vmcnt(0)" ::: "memory");
  __builtin_amdgcn_sched_barrier(0);
#undef TILE
#undef STGALL

#pragma unroll
  for (int i = 0; i < 4; i++) {
#pragma unroll
    for (int j = 0; j < 2; j++) {
#pragma unroll
      for (int e = 0; e < 4; e++) {
        int gr = m0 + wm * 64 + i * 16 + f16 * 4 + e;
        int gc = n0 + wn * 32 + j * 16 + fr;
        if (gr < Mr && gc < Nr) {
          float v = acc[i][j][e];
          if (EPI & EPI_BIAS) v += bias[gc];
          if (EPI & EPI_GELU) v = 0.5f * v * (1.0f + erff(v * 0.70710678118f));
          if (EPI & EPI_PE) v += ((const float*)aux)[((long)(gr & 1023) << 10) + gc];
          long idx = (long)gr * ldc + gc;
          if (EPI & EPI_ACCUM) v += ((float*)C)[idx];
          if (EPI & EPI_OUTBF) ((unsigned short*)C)[idx] = f2bu(v);
          else ((float*)C)[idx] = v;
          if (EPI & EPI_DUP) ((unsigned short*)aux)[idx] = f2bu(v);
        }
      }
    }
  }
}

// ================= legacy batched GEMM, shape-templated tile MB x NB =================
template <int EPI, int MB, int NB>
__global__ __launch_bounds__(256) void gemm_k(
    const unsigned short* __restrict__ Aall, const unsigned short* __restrict__ Btall,
    const float* __restrict__ bias, void* __restrict__ Call, const float* __restrict__ rsall,
    int Mr, int Nr, int Kr, int lda, int ldb, int ldc, int bdiv,
    long As1, long As2, long Bs1, long Bs2, long Cs1, long Cs2, long Rs1, long Rs2) {
  __shared__ unsigned short smA[MB * 32];
  __shared__ unsigned short smB[NB * 32];
  constexpr int WRN = (MB == 128 && NB == 128) ? 2 : (MB == 128 ? 4 : 1);
  constexpr int WCN = 4 / WRN;
  constexpr int MT = MB / WRN, NTW = NB / WCN;
  constexpr int AF = MT / 16, BF = NTW / 16;
  int bz = blockIdx.z;
  const unsigned short* A = Aall + (long)(bz / bdiv) * As1 + (long)(bz % bdiv) * As2;
  const unsigned short* Bt = Btall + (long)(bz / bdiv) * Bs1 + (long)(bz % bdiv) * Bs2;
  long coff = (long)(bz / bdiv) * Cs1 + (long)(bz % bdiv) * Cs2;
  const float* rs = nullptr;
  if (EPI & EPI_RSCALE) rs = rsall + (long)(bz / bdiv) * Rs1 + (long)(bz % bdiv) * Rs2;

  int tid = threadIdx.x, wv = tid >> 6, ll = tid & 63;
  int m0 = blockIdx.x * MB, n0 = blockIdx.y * NB;
  int sr = tid >> 2, sc = (tid & 3) * 8;
  long ar0 = min(m0 + sr, Mr - 1);
  long ar1 = (MB == 128) ? min(m0 + sr + 64, (long)Mr - 1) : 0;
  long br0 = min(n0 + sr, Nr - 1);
  long br1 = (NB == 128) ? min(n0 + sr + 64, (long)Nr - 1) : 0;
  unsigned short* lA0 = &smA[(wv * 16) * 32];
  unsigned short* lA1 = &smA[(64 + wv * 16) * 32];
  unsigned short* lB0 = &smB[(wv * 16) * 32];
  unsigned short* lB1 = &smB[(64 + wv * 16) * 32];

  f32x4 acc[AF][BF] = {};
  int wr = (WRN == 1) ? 0 : ((WRN == 2) ? (wv >> 1) * MT : wv * MT);
  int wc = (WCN == 1) ? 0 : ((WCN == 2) ? (wv & 1) * NTW : wv * NTW);
  int fr = ll & 15, fk = (ll >> 4) * 8;

  for (int k0 = 0; k0 < Kr; k0 += 32) {
    __syncthreads();
    gl_lds16(A + ar0 * lda + k0 + sc, lA0);
    if (MB == 128) gl_lds16(A + ar1 * lda + k0 + sc, lA1);
    gl_lds16(Bt + br0 * ldb + k0 + sc, lB0);
    if (NB == 128) gl_lds16(Bt + br1 * ldb + k0 + sc, lB1);
    __syncthreads();
    u16x8 af[AF], bfr[BF];
#pragma unroll
    for (int i = 0; i < AF; i++) af[i] = *(const u16x8*)&smA[(wr + i * 16 + fr) * 32 + fk];
#pragma unroll
    for (int j = 0; j < BF; j++) bfr[j] = *(const u16x8*)&smB[(wc + j * 16 + fr) * 32 + fk];
#pragma unroll
    for (int i = 0; i < AF; i++)
#pragma unroll
      for (int j = 0; j < BF; j++) acc[i][j] = mfma16(af[i], bfr[j], acc[i][j]);
  }

#pragma unroll
  for (int i = 0; i < AF; i++) {
#pragma unroll
    for (int j = 0; j < BF; j++) {
#pragma unroll
      for (int e = 0; e < 4; e++) {
        int gr = m0 + wr + i * 16 + (ll >> 4) * 4 + e;
        int gc = n0 + wc + j * 16 + (ll & 15);
        if (gr < Mr && gc < Nr) {
          float v = acc[i][j][e];
          if (EPI & EPI_BIAS) v += bias[gc];
          if (EPI & EPI_GELU) v = 0.5f * v * (1.0f + erff(v * 0.70710678118f));
          if (EPI & EPI_RSCALE) v *= rs[gr];
          long idx = coff + (long)gr * ldc + gc;
          if (EPI & EPI_ACCUM) v += ((float*)Call)[idx];
          if (EPI & EPI_OUTBF) ((unsigned short*)Call)[idx] = f2bu(v);
          else ((float*)Call)[idx] = v;
        }
      }
    }
  }
}

// ================= fused FAVOR+ kernels =================
DEVFN void feat_dd(const unsigned short* __restrict__ src, const unsigned short* __restrict__ projc,
                   unsigned short* ldsq, unsigned short* ldsp, int b, int t0, int hh,
                   f32x4 acc[16]) {
  int tid = threadIdx.x, wv = tid >> 6, ll = tid & 63;
#pragma unroll
  for (int p = 0; p < 2; p++) {
    int r = p * 64 + (tid >> 3), c8 = (tid & 7) * 8;
    *(u16x8*)&ldsq[r * 72 + c8] =
        *(const u16x8*)&src[((long)b * CT + t0 + r) * CQKV + hh * CDH + c8];
  }
#pragma unroll
  for (int p = 0; p < 4; p++) {
    int r = p * 64 + (tid >> 3), c8 = (tid & 7) * 8;
    *(u16x8*)&ldsp[r * 72 + c8] = *(const u16x8*)&projc[r * 64 + c8];
  }
  __syncthreads();
  int fr = ll & 15, fk = (ll >> 4) * 8;
#pragma unroll
  for (int ks = 0; ks < 2; ks++) {
    u16x8 af = *(const u16x8*)&ldsq[(wv * 16 + fr) * 72 + ks * 32 + fk];
#pragma unroll
    for (int j = 0; j < 16; j++) {
      u16x8 bf = *(const u16x8*)&ldsp[(j * 16 + fr) * 72 + ks * 32 + fk];
      acc[j] = mfma16(af, bf, acc[j]);
    }
  }
}

__global__ __launch_bounds__(512, 4) void kstab_f(const unsigned short* __restrict__ kb,
                                                  const unsigned short* __restrict__ projc,
                                                  float* __restrict__ part) {
  extern __shared__ char dynsm[];
  unsigned short* ldsq = (unsigned short*)dynsm;            // [128][72]
  unsigned short* ldsp = (unsigned short*)(dynsm + 18432);  // [256][72]
  __shared__ float smx[8];
  int bh = blockIdx.x >> 3, chunk = blockIdx.x & 7;
  int b = bh >> 4, hh = bh & 15;
  f32x4 acc[16] = {};
  feat_dd(kb, projc, ldsq, ldsp, b, chunk * 128, hh, acc);
  float mx = -3.4e38f;
#pragma unroll
  for (int j = 0; j < 16; j++)
#pragma unroll
    for (int e = 0; e < 4; e++) mx = fmaxf(mx, acc[j][e]);
  mx = wredmax(mx);
  int wv = threadIdx.x >> 6;
  if ((threadIdx.x & 63) == 0) smx[wv] = mx;
  __syncthreads();
  if (threadIdx.x == 0) {
    float m2 = smx[0];
#pragma unroll
    for (int i = 1; i < 8; i++) m2 = fmaxf(m2, smx[i]);
    part[blockIdx.x] = m2;
  }
}

__global__ __launch_bounds__(512, 4) void featk_f(const unsigned short* __restrict__ kb,
                                                  const unsigned short* __restrict__ projc,
                                                  const float* __restrict__ part,
                                                  unsigned short* __restrict__ kpt,
                                                  float* __restrict__ kspart) {
  extern __shared__ char dynsm[];
  unsigned short* ldsq = (unsigned short*)dynsm;            // [128][72]
  unsigned short* ldsp = (unsigned short*)(dynsm + 18432);  // [256][72]
  unsigned short* ldso = (unsigned short*)dynsm;            // overlay [256][136]
  int tid = threadIdx.x, wv = tid >> 6, ll = tid & 63;
  int bh = blockIdx.x >> 3, chunk = blockIdx.x & 7;
  int b = bh >> 4, hh = bh & 15;
  float st = part[bh * 8];
#pragma unroll
  for (int i = 1; i < 8; i++) st = fmaxf(st, part[bh * 8 + i]);
  f32x4 acc[16] = {};
  feat_dd(kb, projc, ldsq, ldsp, b, chunk * 128, hh, acc);
  int fr = ll & 15, g = ll >> 4;
  float diag[4];
#pragma unroll
  for (int e = 0; e < 4; e++) {
    int row = wv * 16 + g * 4 + e;
    u16x4 kv = *(const u16x4*)&ldsq[row * 72 + fr * 4];
    float s = 0;
#pragma unroll
    for (int z = 0; z < 4; z++) { float f = b2f(kv[z]); s += f * f; }
#pragma unroll
    for (int o = 1; o < 16; o <<= 1) s += __shfl_xor(s, o, 64);
    diag[e] = s * (0.5f * CDN * CDN);
  }
  __syncthreads();
#pragma unroll
  for (int j = 0; j < 16; j++)
#pragma unroll
    for (int e = 0; e < 4; e++) {
      float v = CRATIO * (expf(acc[j][e] - diag[e] - st) + CKEPS);
      ldso[(j * 16 + fr) * 136 + wv * 16 + g * 4 + e] = f2bu(v);
    }
  __syncthreads();
  int m = tid >> 1, seg = (tid & 1) * 64;
  long base = ((long)bh * CM + m) * CT + chunk * 128;
  float ks = 0;
#pragma unroll
  for (int z = 0; z < 8; z++) {
    u16x8 v8 = *(u16x8*)&ldso[m * 136 + seg + z * 8];
    *(u16x8*)&kpt[base + seg + z * 8] = v8;
#pragma unroll
    for (int w = 0; w < 8; w++) ks += b2f(v8[w]);
  }
  ks += __shfl_xor(ks, 1, 64);
  if ((tid & 1) == 0) kspart[((long)bh * 8 + chunk) * CM + m] = ks;
}

// queries: dd -> row-max -> qp bf16 + fused ksum-reduce + dinv
__global__ __launch_bounds__(512, 4) void featq_f(const unsigned short* __restrict__ qb,
                                                  const unsigned short* __restrict__ projc,
                                                  const float* __restrict__ kspart,
                                                  unsigned short* __restrict__ qp,
                                                  float* __restrict__ dinv) {
  extern __shared__ char dynsm[];
  unsigned short* ldsq = (unsigned short*)dynsm;            // [128][72]
  unsigned short* ldsp = (unsigned short*)(dynsm + 18432);  // [256][72]
  unsigned short* ldso = (unsigned short*)dynsm;            // overlay [128][264]
  float* ldks = (float*)(dynsm + 67584);                    // [256]
  int tid = threadIdx.x, wv = tid >> 6, ll = tid & 63;
  int bh = blockIdx.x >> 3, chunk = blockIdx.x & 7;
  int b = bh >> 4, hh = bh & 15;
  int t0 = chunk * 128;
  if (tid < 256) {
    float s = 0;
#pragma unroll
    for (int c = 0; c < 8; c++) s += kspart[((long)bh * 8 + c) * CM + tid];
    ldks[tid] = s;
  }
  f32x4 acc[16] = {};
  feat_dd(qb, projc, ldsq, ldsp, b, t0, hh, acc);
  int fr = ll & 15, g = ll >> 4;
  float rmax[4], diag[4];
#pragma unroll
  for (int e = 0; e < 4; e++) {
    float mx = acc[0][e];
#pragma unroll
    for (int j = 1; j < 16; j++) mx = fmaxf(mx, acc[j][e]);
#pragma unroll
    for (int o = 1; o < 16; o <<= 1) mx = fmaxf(mx, __shfl_xor(mx, o, 64));
    rmax[e] = mx;
    int row = wv * 16 + g * 4 + e;
    u16x4 qv = *(const u16x4*)&ldsq[row * 72 + fr * 4];
    float s = 0;
#pragma unroll
    for (int z = 0; z < 4; z++) { float f = b2f(qv[z]); s += f * f; }
#pragma unroll
    for (int o = 1; o < 16; o <<= 1) s += __shfl_xor(s, o, 64);
    diag[e] = s * (0.5f * CDN * CDN);
  }
  __syncthreads();
#pragma unroll
  for (int j = 0; j < 16; j++)
#pragma unroll
    for (int e = 0; e < 4; e++) {
      float v = CRATIO * (expf(acc[j][e] - diag[e] - rmax[e]) + CKEPS);
      ldso[(wv * 16 + g * 4 + e) * 264 + j * 16 + fr] = f2bu(v);
    }
  __syncthreads();
  int row = tid >> 2, seg = (tid & 3) * 64;
  long base = ((long)bh * CT + t0) * CM;
  float dot = 0;
#pragma unroll
  for (int z = 0; z < 8; z++) {
    u16x8 v8 = *(u16x8*)&ldso[row * 264 + seg + z * 8];
    *(u16x8*)&qp[base + (long)row * CM + seg + z * 8] = v8;
#pragma unroll
    for (int w = 0; w < 8; w++) dot += b2f(v8[w]) * ldks[seg + z * 8 + w];
  }
  dot += __shfl_xor(dot, 1, 64);
  dot += __shfl_xor(dot, 2, 64);
  if ((tid & 3) == 0) dinv[(long)bh * CT + t0 + row] = 1.0f / dot;
}

// ---------------- LayerNorm ----------------
__global__ __launch_bounds__(256) void ln_k(const float* __restrict__ h,
                                            const float* __restrict__ g,
                                            const float* __restrict__ b,
                                            unsigned short* __restrict__ y) {
  int wv = threadIdx.x >> 6, ll = threadIdx.x & 63;
  long row = (long)blockIdx.x * 4 + wv;
  const float* hr = h + row * CDM;
  f32x4 x[4];
#pragma unroll
  for (int i = 0; i < 4; i++) x[i] = *(const f32x4*)&hr[ll * 16 + i * 4];
  float s = 0;
#pragma unroll
  for (int i = 0; i < 4; i++)
#pragma unroll
    for (int e = 0; e < 4; e++) s += x[i][e];
  float mu = wredsum(s) * (1.f / CDM);
  float v = 0;
#pragma unroll
  for (int i = 0; i < 4; i++)
#pragma unroll
    for (int e = 0; e < 4; e++) {
      float d = x[i][e] - mu;
      v += d * d;
    }
  float inv = rsqrtf(wredsum(v) * (1.f / CDM) + 1e-5f);
  unsigned short o[16];
#pragma unroll
  for (int i = 0; i < 4; i++)
#pragma unroll
    for (int e = 0; e < 4; e++) {
      int c = ll * 16 + i * 4 + e;
      o[i * 4 + e] = f2bu((x[i][e] - mu) * inv * g[c] + b[c]);
    }
  *(u16x8*)&y[row * CDM + ll * 16] = *(u16x8*)&o[0];
  *(u16x8*)&y[row * CDM + ll * 16 + 8] = *(u16x8*)&o[8];
}

// ---------------- v -> v_t ----------------
__global__ __launch_bounds__(256) void trv_k(const unsigned short* __restrict__ vb,
                                             unsigned short* __restrict__ vt) {
  int bh = blockIdx.x >> 5;
  int t0 = (blockIdx.x & 31) * 32;
  int b = bh >> 4, hh = bh & 15;
  __shared__ unsigned short tile[32][64];
  int tr = threadIdx.x >> 3, dblk = (threadIdx.x & 7) * 8;
  *(u16x8*)&tile[tr][dblk] = *(const u16x8*)&vb[((long)b * CT + t0 + tr) * CQKV + hh * CDH + dblk];
  __syncthreads();
  int d = threadIdx.x >> 2, tz = (threadIdx.x & 3) * 8;
  unsigned short o[8];
#pragma unroll
  for (int e = 0; e < 8; e++) o[e] = tile[tz + e][d];
  *(u16x8*)&vt[((long)bh * CDH + d) * CT + t0 + tz] = *(u16x8*)&o[0];
}

// ---------------- fp32 -> bf16 flat ----------------
__global__ __launch_bounds__(256) void f2b_k(const float* __restrict__ in,
                                             unsigned short* __restrict__ out, long n) {
  long i = ((long)blockIdx.x * 256 + threadIdx.x) * 4;
  if (i >= n) return;
  f32x4 v = *(const f32x4*)&in[i];
  unsigned short o[4];
#pragma unroll
  for (int e = 0; e < 4; e++) o[e] = f2bu(v[e]);
  *(u16x4*)&out[i] = *(u16x4*)&o[0];
}

// ---------------- z-batched transpose-convert ----------------
__global__ __launch_bounds__(256) void tconvz_k(const float* __restrict__ in,
                                                unsigned short* __restrict__ out, int R, int C,
                                                long szs, long dzs) {
  const float* src = in + (long)blockIdx.z * szs;
  unsigned short* dst = out + (long)blockIdx.z * dzs;
  __shared__ float tile[32][33];
  int r0 = blockIdx.x * 32, c0 = blockIdx.y * 32;
  int tr = threadIdx.x >> 5, tc = threadIdx.x & 31;
#pragma unroll
  for (int p = 0; p < 4; p++) {
    int r = r0 + p * 8 + tr, c = c0 + tc;
    tile[p * 8 + tr][tc] = (r < R && c < C) ? src[(long)r * C + c] : 0.f;
  }
  __syncthreads();
#pragma unroll
  for (int p = 0; p < 4; p++) {
    int c = c0 + p * 8 + tr, r = r0 + tc;
    if (c < C && r < R) dst[(long)c * R + r] = f2bu(tile[tc][p * 8 + tr]);
  }
}

// ---------------- Wconv -> per-tap bf16: [r][oc][ic] = (192,1024) ----------------
__global__ __launch_bounds__(256) void wconv_k(const float* __restrict__ W,
                                               unsigned short* __restrict__ out) {
  int idx = blockIdx.x * 256 + threadIdx.x;
  int r = idx >> 16, rem = idx & 65535, oc = rem >> 10, ic = rem & 1023;
  out[idx] = f2bu(W[oc * 3072 + ic * 3 + r]);
}

// ---------------- conv tap-mix, EXACT zero-padding at per-batch boundaries ----------------
__global__ __launch_bounds__(256) void convmix_k(const float* __restrict__ Y,
                                                 const float* __restrict__ bc,
                                                 float* __restrict__ xa) {
  long t = (long)blockIdx.x * 4 + (threadIdx.x >> 6);
  int oc = threadIdx.x & 63;
  int tb = (int)(t & 1023);
  float v = Y[t * 192 + 64 + oc] + bc[oc];
  if (tb != 0) v += Y[(t - 1) * 192 + oc];          // r=0 tap uses h[t-1]; zero at batch start
  if (tb != 1023) v += Y[(t + 1) * 192 + 128 + oc]; // r=2 tap uses h[t+1]; zero at batch end
  xa[t * 64 + oc] = v;
}

// ---------------- proj * dn -> bf16 ----------------
__global__ __launch_bounds__(256) void projc_k(const float* __restrict__ p,
                                               unsigned short* __restrict__ out) {
  int i = blockIdx.x * 256 + threadIdx.x;
  out[i] = f2bu(p[i] * CDN);
}

// ---------------- concat q/k/v biases (z = layer) ----------------
__global__ __launch_bounds__(256) void catb_k(const float* __restrict__ q,
                                              const float* __restrict__ k,
                                              const float* __restrict__ v,
                                              float* __restrict__ o) {
  int l = blockIdx.y;
  int i = blockIdx.x * 256 + threadIdx.x;  // < 3072
  float val = i < 1024 ? q[l * CDM + i] : (i < 2048 ? k[l * CDM + i - 1024] : v[l * CDM + i - 2048]);
  o[l * CQKV + i] = val;
}

#define LAUNCH_GEMM(EPI, MB, NB, A, Bt, bias, C, rsp, Mr, Nr, Kr, lda, ldb, ldc, nb, bdiv, As1, As2, Bs1, Bs2, Cs1, Cs2, Rs1, Rs2) \
  gemm_k<EPI, MB, NB><<<dim3(((Mr) + (MB)-1) / (MB), ((Nr) + (NB)-1) / (NB), (nb)), 256, 0, stream>>>( \
      (const unsigned short*)(A), (const unsigned short*)(Bt), (bias), (void*)(C), (rsp),        \
      (Mr), (Nr), (Kr), (lda), (ldb), (ldc), (bdiv), (long)(As1), (long)(As2), (long)(Bs1),      \
      (long)(Bs2), (long)(Cs1), (long)(Cs2), (long)(Rs1), (long)(Rs2))

#define LAUNCH_G1(EPI, A, Bt, bias, C, AUX, Mr, Nr, Kr, lda, ldb, ldc)                           \
  gemm128_k<EPI><<<dim3(((Mr) + 127) / 128, ((Nr) + 127) / 128), 512, 0, stream>>>(              \
      (const unsigned short*)(A), (const unsigned short*)(Bt), (bias), (void*)(C), (void*)(AUX), \
      (Mr), (Nr), (Kr), (lda), (ldb), (ldc))

extern "C" void kernel_launch(void* const* d_in, const int* in_sizes, int n_in,
                              void* d_out, int out_size, void* d_ws, size_t ws_size,
                              hipStream_t stream) {
  const float* x = (const float*)d_in[0];
  const float* Win = (const float*)d_in[1];
  const float* b_in = (const float*)d_in[2];
  const float* pe = (const float*)d_in[3];
  const float* ln1_g = (const float*)d_in[4];
  const float* ln1_b = (const float*)d_in[5];
  const float* Wq = (const float*)d_in[6];
  const float* bq = (const float*)d_in[7];
  const float* Wk = (const float*)d_in[8];
  const float* bk = (const float*)d_in[9];
  const float* Wv = (const float*)d_in[10];
  const float* bv = (const float*)d_in[11];
  const float* Wo = (const float*)d_in[12];
  const float* bo = (const float*)d_in[13];
  const float* ln2_g = (const float*)d_in[14];
  const float* ln2_b = (const float*)d_in[15];
  const float* W1 = (const float*)d_in[16];
  const float* b1 = (const float*)d_in[17];
  const float* W2 = (const float*)d_in[18];
  const float* b2 = (const float*)d_in[19];
  const float* Wc = (const float*)d_in[20];
  const float* bc = (const float*)d_in[21];
  const float* Wconv = (const float*)d_in[22];
  const float* bconv = (const float*)d_in[23];
  const float* Waux = (const float*)d_in[24];
  const float* baux = (const float*)d_in[25];
  const float* proj = (const float*)d_in[26];
  float* out = (float*)d_out;

  char* wsp = (char*)d_ws;
  size_t off = 0;
  auto take = [&](size_t bytes) {
    char* p = wsp + off;
    off = (off + bytes + 255) & ~(size_t)255;
    return p;
  };
  float* h_f = (float*)take(33554432);                      // (8192,1024) fp32 residual
  unsigned short* y_bf = (unsigned short*)take(16777216);   // LN out; aliased: vt, o
  unsigned short* qkv_bf = (unsigned short*)take(50331648); // (8192,3072) fused q,k,v
  unsigned short* qp_bf = (unsigned short*)take(67108864);  // (B,H,T,M)
  unsigned short* kpt_bf = (unsigned short*)take(67108864); // (B,H,M,T)
  unsigned short* ff_bf = (unsigned short*)take(67108864);  // (8192,4096) FFN mid
  unsigned short* ctx_bf = (unsigned short*)take(4194304);  // (B,H,DH,M)
  float* kspart_f = (float*)take(1048576);                  // (bh,8,256)
  float* kstab_f_buf = (float*)take(4096);                  // (bh,8)
  float* dinv_f = (float*)take(524288);
  float* xa_f = (float*)take(2097152);
  float* ycv_f = (float*)take(6291456);                     // (8192,192) conv taps
  unsigned short* xabf = (unsigned short*)take(1048576);
  float* bqkv_f = (float*)take(24576);                      // 2 layers x 3072
  unsigned short* hbf = (unsigned short*)take(16777216);    // bf16 dual-write of h
  unsigned short* xbf = (unsigned short*)take(4194304);
  unsigned short* win_t = (unsigned short*)take(524288);
  unsigned short* wqkvo_t = (unsigned short*)take(16777216);
  unsigned short* w1_t = (unsigned short*)take(16777216);
  unsigned short* w2_t = (unsigned short*)take(16777216);
  unsigned short* wc_t = (unsigned short*)take(4096000);
  unsigned short* projc = (unsigned short*)take(32768);
  unsigned short* wconv_t = (unsigned short*)take(393216);
  unsigned short* waux_t = (unsigned short*)take(256128);
  unsigned short* vt_bf = y_bf;                    // alias (y dead after QKV)
  unsigned short* o_bf = y_bf;                     // alias (vt dead after ctx)
  (void)in_sizes; (void)n_in; (void)out_size; (void)ws_size;

  // ---- weight conversion (z-batched) ----
  f2b_k<<<2048, 256, 0, stream>>>(x, xbf, (long)CNT * 256);
  tconvz_k<<<dim3(8, 32, 1), 256, 0, stream>>>(Win, win_t, 256, 1024, 0, 0);
  tconvz_k<<<dim3(32, 32, 2), 256, 0, stream>>>(Wq, wqkvo_t + 0 * 1048576, 1024, 1024, 1048576, 4194304);
  tconvz_k<<<dim3(32, 32, 2), 256, 0, stream>>>(Wk, wqkvo_t + 1 * 1048576, 1024, 1024, 1048576, 4194304);
  tconvz_k<<<dim3(32, 32, 2), 256, 0, stream>>>(Wv, wqkvo_t + 2 * 1048576, 1024, 1024, 1048576, 4194304);
  tconvz_k<<<dim3(32, 32, 2), 256, 0, stream>>>(Wo, wqkvo_t + 3 * 1048576, 1024, 1024, 1048576, 4194304);
  tconvz_k<<<dim3(32, 128, 2), 256, 0, stream>>>(W1, w1_t, 1024, 4096, 4194304, 4194304);
  tconvz_k<<<dim3(128, 32, 2), 256, 0, stream>>>(W2, w2_t, 4096, 1024, 4194304, 4194304);
  tconvz_k<<<dim3(32, 63, 1), 256, 0, stream>>>(Wc, wc_t, 1024, 2000, 0, 0);
  tconvz_k<<<dim3(2, 63, 1), 256, 0, stream>>>(Waux, waux_t, 64, 2001, 0, 0);
  catb_k<<<dim3(12, 2), 256, 0, stream>>>(bq, bk, bv, bqkv_f);
  wconv_k<<<768, 256, 0, stream>>>(Wconv, wconv_t);
  projc_k<<<64, 256, 0, stream>>>(proj, projc);

  // ---- embed (+pe fused) ----
  LAUNCH_G1(EPI_BIAS | EPI_PE, xbf, win_t, b_in, h_f, pe, CNT, CDM, 256, 256, 256, CDM);

  for (int l = 0; l < 2; l++) {
    const unsigned short* wqkv_t = wqkvo_t + (long)(l * 4) * 1048576;  // q,k,v adjacent
    const unsigned short* wo_t = wqkvo_t + (long)(l * 4 + 3) * 1048576;

    ln_k<<<2048, 256, 0, stream>>>(h_f, ln1_g + l * CDM, ln1_b + l * CDM, y_bf);
    LAUNCH_G1(EPI_BIAS | EPI_OUTBF, y_bf, wqkv_t, bqkv_f + l * CQKV, qkv_bf, nullptr, CNT, CQKV, CDM, CDM, CDM, CQKV);

    // fused FAVOR+: keys (2 passes) then queries (+ksum reduce + dinv)
    kstab_f<<<1024, 512, 55296, stream>>>(qkv_bf + 1024, projc, kstab_f_buf);
    featk_f<<<1024, 512, 69632, stream>>>(qkv_bf + 1024, projc, kstab_f_buf, kpt_bf, kspart_f);
    featq_f<<<1024, 512, 68608, stream>>>(qkv_bf, projc, kspart_f, qp_bf, dinv_f);
    trv_k<<<4096, 256, 0, stream>>>(qkv_bf + 2048, vt_bf);
    // ctx^T (DH,M) = v^T @ kp, batched — 64x128 tiles
    LAUNCH_GEMM(EPI_OUTBF, 64, 128, vt_bf, kpt_bf, nullptr, ctx_bf, nullptr, CDH, CM, CT, CT, CT, CM, 128, CH,
                (long)CH * CDH * CT, (long)CDH * CT, (long)CH * CM * CT, (long)CM * CT,
                (long)CH * CDH * CM, (long)CDH * CM, 0, 0);
    // o = (qp @ ctx) * dinv — 128x64 tiles
    LAUNCH_GEMM(EPI_RSCALE | EPI_OUTBF, 128, 64, qp_bf, ctx_bf, nullptr, o_bf, dinv_f, CT, CDH, CM, CM, CM, CDM, 128, CH,
                (long)CH * CT * CM, (long)CT * CM, (long)CH * CDH * CM, (long)CDH * CM,
                (long)CT * CDM, 64, (long)CH * CT, (long)CT);
    LAUNCH_G1(EPI_BIAS | EPI_ACCUM, o_bf, wo_t, bo + l * CDM, h_f, nullptr, CNT, CDM, CDM, CDM, CDM, CDM);

    ln_k<<<2048, 256, 0, stream>>>(h_f, ln2_g + l * CDM, ln2_b + l * CDM, y_bf);
    LAUNCH_G1(EPI_BIAS | EPI_GELU | EPI_OUTBF, y_bf, w1_t + (long)l * 4194304, b1 + l * CDFF, ff_bf, nullptr,
              CNT, CDFF, CDM, CDM, CDM, CDFF);
    // FFN2: accumulate into fp32 h AND write bf16 copy (feeds conv / classifier)
    LAUNCH_G1(EPI_BIAS | EPI_ACCUM | EPI_DUP, ff_bf, w2_t + (long)l * 4194304, b2 + l * CDM, h_f, hbf,
              CNT, CDM, CDFF, CDFF, CDFF, CDM);

    if (l == 0) {
      // conv1d: single N=192 GEMM over 3 taps + exact boundary tap-mix
      LAUNCH_GEMM(0, 128, 128, hbf, wconv_t, nullptr, ycv_f, nullptr, CNT, 192, CDM, CDM, CDM, 192, 1, 1, 0, 0, 0, 0, 0, 0, 0, 0);
      convmix_k<<<2048, 256, 0, stream>>>(ycv_f, bconv, xa_f);
      f2b_k<<<512, 256, 0, stream>>>(xa_f, xabf, (long)CNT * 64);
      LAUNCH_GEMM(EPI_BIAS, 128, 128, xabf, waux_t, baux, out + 16384000, nullptr, CNT, CV + 1, 64, 64, 64, CV + 1, 1, 1, 0, 0, 0, 0, 0, 0, 0, 0);
    }
  }

  // ---- classifier (hbf written by layer-1 FFN2 dual-store) ----
  LAUNCH_G1(EPI_BIAS, hbf, wc_t, bc, out, nullptr, CNT, CV, CDM, CDM, CDM, CV);
}

// Round 13
// 1167.470 us; speedup vs baseline: 1.1814x; 1.0398x over previous
//
#include <hip/hip_runtime.h>
#include <hip/hip_bf16.h>

typedef __attribute__((ext_vector_type(4))) float f32x4;
typedef __attribute__((ext_vector_type(8))) unsigned short u16x8;
typedef __attribute__((ext_vector_type(4))) unsigned short u16x4;
typedef __bf16 bf16x8 __attribute__((ext_vector_type(8)));

#define DEVFN static __device__ __forceinline__

constexpr int CB = 8, CT = 1024, CDM = 1024, CH = 16, CDH = 64, CDFF = 4096, CV = 2000, CM = 256;
constexpr int CNT = CB * CT; // 8192 tokens
constexpr int CQKV = 3072;   // fused qkv row stride
constexpr float CDN = 0.35355339059327373f;   // 64^-0.25
constexpr float CRATIO = 0.0625f;             // 256^-0.5
constexpr float CKEPS = 1e-4f;

DEVFN unsigned short f2bu(float x) {
  __hip_bfloat16 h = __float2bfloat16(x);
  return __builtin_bit_cast(unsigned short, h);
}
DEVFN float b2f(unsigned short u) {
  __hip_bfloat16 h = __builtin_bit_cast(__hip_bfloat16, u);
  return __bfloat162float(h);
}
DEVFN float wredsum(float s) {
#pragma unroll
  for (int ofs = 32; ofs; ofs >>= 1) s += __shfl_xor(s, ofs, 64);
  return s;
}
DEVFN float wredmax(float s) {
#pragma unroll
  for (int ofs = 32; ofs; ofs >>= 1) s = fmaxf(s, __shfl_xor(s, ofs, 64));
  return s;
}
DEVFN void gl_lds16(const void* g, void* l) {
  __builtin_amdgcn_global_load_lds(
      (const __attribute__((address_space(1))) unsigned int*)g,
      (__attribute__((address_space(3))) unsigned int*)l, 16, 0, 0);
}
DEVFN f32x4 mfma16(u16x8 a, u16x8 b, f32x4 c) {
  return __builtin_amdgcn_mfma_f32_16x16x32_bf16(
      __builtin_bit_cast(bf16x8, a), __builtin_bit_cast(bf16x8, b), c, 0, 0, 0);
}
// compiler-invisible LDS read; waits are manual (counted lgkmcnt)
DEVFN u16x8 lds_rd128(unsigned addr) {
  u16x8 r;
  asm volatile("ds_read_b128 %0, %1" : "=v"(r) : "v"(addr));
  return r;
}
DEVFN unsigned lds_addr(const void* p) {
  return (unsigned)(unsigned long)(const __attribute__((address_space(3))) char*)p;
}

#define EPI_BIAS 1
#define EPI_ACCUM 2
#define EPI_GELU 4
#define EPI_OUTBF 8
#define EPI_PE 32    // add pe[(row&1023)*1024 + col] (aux = pe fp32)
#define EPI_DUP 64   // also write bf16 copy to aux at same idx

// ================= 128x128 big GEMM (best measured: 122 us FFN-class) =================
// BK=64, 8 waves (2x4), 2 LDS buffers (64KB, 2 blocks/CU, 16 waves/CU), st-swizzle,
// asm ds_read + counted lgkmcnt, full-tile prefetch + counted vmcnt(4), setprio.
template <int EPI>
__global__ __launch_bounds__(512, 4) void gemm128_k(
    const unsigned short* __restrict__ A, const unsigned short* __restrict__ Bt,
    const float* __restrict__ bias, void* __restrict__ C, void* __restrict__ aux,
    int Mr, int Nr, int Kr, int lda, int ldb, int ldc) {
  __shared__ unsigned short smA[2][128 * 64];
  __shared__ unsigned short smB[2][128 * 64];

  int tid = threadIdx.x, wv = tid >> 6, ll = tid & 63;
  int wm = wv >> 2, wn = wv & 3;  // 2 x 4 wave grid; per-wave out 64x32
  int m0 = blockIdx.x * 128, n0 = blockIdx.y * 128;
  int fr = ll & 15, f16 = ll >> 4, fk = f16 * 8;

  const char* Ab = (const char*)A;
  const char* Bb = (const char*)Bt;

  unsigned int offA[2], offB[2];
#pragma unroll
  for (int ro = 0; ro < 2; ro++) {
    int L = (ro * 512 + tid) * 16;
    int P = L ^ (((L >> 9) & 1) << 5);
    int kh = P >> 13, rem = P & 8191;
    int r = rem >> 6, cb = rem & 63;
    long rowA = min(m0 + r, Mr - 1);
    offA[ro] = (unsigned)((rowA * lda + kh * 32) * 2 + cb);
    long rowB = min(n0 + r, Nr - 1);
    offB[ro] = (unsigned)((rowB * ldb + kh * 32) * 2 + cb);
  }
  unsigned aAb = lds_addr(&smA[0][0]), aBb = lds_addr(&smB[0][0]);
  unsigned offArd[4], offBrd[2];
#pragma unroll
  for (int i = 0; i < 4; i++) {
    int r = wm * 64 + i * 16 + fr;
    offArd[i] = aAb + (unsigned)(r * 64 + 2 * (fk ^ (((r >> 3) & 1) << 4)));
  }
#pragma unroll
  for (int j = 0; j < 2; j++) {
    int r = wn * 32 + j * 16 + fr;
    offBrd[j] = aBb + (unsigned)(r * 64 + 2 * (fk ^ (((r >> 3) & 1) << 4)));
  }

  f32x4 acc[4][2] = {};
  int NT = Kr / 64;

#define STGALL(PB, KBN)                                                      \
  {                                                                          \
    _Pragma("unroll") for (int ro = 0; ro < 2; ro++)                         \
        gl_lds16(Ab + offA[ro] + (KBN), &smA[PB][(ro * 512 + wv * 64) * 8]); \
    _Pragma("unroll") for (int ro = 0; ro < 2; ro++)                         \
        gl_lds16(Bb + offB[ro] + (KBN), &smB[PB][(ro * 512 + wv * 64) * 8]); \
  }
#define TILE(PB, KBN)                                                        \
  {                                                                          \
    __builtin_amdgcn_s_barrier();                                            \
    __builtin_amdgcn_sched_barrier(0);                                       \
    STGALL((PB) ^ 1, KBN);                                                   \
    asm volatile("s_waitcnt vmcnt(4)" ::: "memory");                         \
    __builtin_amdgcn_sched_barrier(0);                                       \
    __builtin_amdgcn_s_barrier();                                            \
    __builtin_amdgcn_sched_barrier(0);                                       \
    u16x8 a0[4], b0[2], a1[4], b1[2];                                        \
    _Pragma("unroll") for (int i = 0; i < 4; i++)                            \
        a0[i] = lds_rd128(offArd[i] + (PB)*16384);                           \
    _Pragma("unroll") for (int j = 0; j < 2; j++)                            \
        b0[j] = lds_rd128(offBrd[j] + (PB)*16384);                           \
    _Pragma("unroll") for (int i = 0; i < 4; i++)                            \
        a1[i] = lds_rd128(offArd[i] + (PB)*16384 + 8192);                    \
    _Pragma("unroll") for (int j = 0; j < 2; j++)                            \
        b1[j] = lds_rd128(offBrd[j] + (PB)*16384 + 8192);                    \
    asm volatile("s_waitcnt lgkmcnt(6)" ::: "memory");                       \
    __builtin_amdgcn_sched_barrier(0);                                       \
    __builtin_amdgcn_s_setprio(1);                                           \
    _Pragma("unroll") for (int i = 0; i < 4; i++) {                          \
      acc[i][0] = mfma16(a0[i], b0[0], acc[i][0]);                           \
      acc[i][1] = mfma16(a0[i], b0[1], acc[i][1]);                           \
    }                                                                        \
    __builtin_amdgcn_s_setprio(0);                                           \
    asm volatile("s_waitcnt lgkmcnt(0)" ::: "memory");                       \
    __builtin_amdgcn_sched_barrier(0);                                       \
    __builtin_amdgcn_s_setprio(1);                                           \
    _Pragma("unroll") for (int i = 0; i < 4; i++) {                          \
      acc[i][0] = mfma16(a1[i], b1[0], acc[i][0]);                           \
      acc[i][1] = mfma16(a1[i], b1[1], acc[i][1]);                           \
    }                                                                        \
    __builtin_amdgcn_s_setprio(0);                                           \
  }

  STGALL(0, 0);
  for (int t = 0; t < NT; t += 2) {
    long kb1 = (long)(t + 1) * 128;
    long kb2 = (long)min(t + 2, NT - 1) * 128;
    TILE(0, kb1);
    TILE(1, kb2);
  }
  asm volatile("s_waitcnt vmcnt(0)" ::: "memory");
  __builtin_amdgcn_sched_barrier(0);
#undef TILE
#undef STGALL

#pragma unroll
  for (int i = 0; i < 4; i++) {
#pragma unroll
    for (int j = 0; j < 2; j++) {
#pragma unroll
      for (int e = 0; e < 4; e++) {
        int gr = m0 + wm * 64 + i * 16 + f16 * 4 + e;
        int gc = n0 + wn * 32 + j * 16 + fr;
        if (gr < Mr && gc < Nr) {
          float v = acc[i][j][e];
          if (EPI & EPI_BIAS) v += bias[gc];
          if (EPI & EPI_GELU) v = 0.5f * v * (1.0f + erff(v * 0.70710678118f));
          if (EPI & EPI_PE) v += ((const float*)aux)[((long)(gr & 1023) << 10) + gc];
          long idx = (long)gr * ldc + gc;
          if (EPI & EPI_ACCUM) v += ((float*)C)[idx];
          if (EPI & EPI_OUTBF) ((unsigned short*)C)[idx] = f2bu(v);
          else ((float*)C)[idx] = v;
          if (EPI & EPI_DUP) ((unsigned short*)aux)[idx] = f2bu(v);
        }
      }
    }
  }
}

// ================= legacy batched GEMM, shape-templated tile MB x NB =================
template <int EPI, int MB, int NB>
__global__ __launch_bounds__(256) void gemm_k(
    const unsigned short* __restrict__ Aall, const unsigned short* __restrict__ Btall,
    const float* __restrict__ bias, void* __restrict__ Call,
    int Mr, int Nr, int Kr, int lda, int ldb, int ldc, int bdiv,
    long As1, long As2, long Bs1, long Bs2, long Cs1, long Cs2) {
  __shared__ unsigned short smA[MB * 32];
  __shared__ unsigned short smB[NB * 32];
  constexpr int WRN = (MB == 128 && NB == 128) ? 2 : (MB == 128 ? 4 : 1);
  constexpr int WCN = 4 / WRN;
  constexpr int MT = MB / WRN, NTW = NB / WCN;
  constexpr int AF = MT / 16, BF = NTW / 16;
  int bz = blockIdx.z;
  const unsigned short* A = Aall + (long)(bz / bdiv) * As1 + (long)(bz % bdiv) * As2;
  const unsigned short* Bt = Btall + (long)(bz / bdiv) * Bs1 + (long)(bz % bdiv) * Bs2;
  long coff = (long)(bz / bdiv) * Cs1 + (long)(bz % bdiv) * Cs2;

  int tid = threadIdx.x, wv = tid >> 6, ll = tid & 63;
  int m0 = blockIdx.x * MB, n0 = blockIdx.y * NB;
  int sr = tid >> 2, sc = (tid & 3) * 8;
  long ar0 = min(m0 + sr, Mr - 1);
  long ar1 = (MB == 128) ? min(m0 + sr + 64, (long)Mr - 1) : 0;
  long br0 = min(n0 + sr, Nr - 1);
  long br1 = (NB == 128) ? min(n0 + sr + 64, (long)Nr - 1) : 0;
  unsigned short* lA0 = &smA[(wv * 16) * 32];
  unsigned short* lA1 = &smA[(64 + wv * 16) * 32];
  unsigned short* lB0 = &smB[(wv * 16) * 32];
  unsigned short* lB1 = &smB[(64 + wv * 16) * 32];

  f32x4 acc[AF][BF] = {};
  int wr = (WRN == 1) ? 0 : ((WRN == 2) ? (wv >> 1) * MT : wv * MT);
  int wc = (WCN == 1) ? 0 : ((WCN == 2) ? (wv & 1) * NTW : wv * NTW);
  int fr = ll & 15, fk = (ll >> 4) * 8;

  for (int k0 = 0; k0 < Kr; k0 += 32) {
    __syncthreads();
    gl_lds16(A + ar0 * lda + k0 + sc, lA0);
    if (MB == 128) gl_lds16(A + ar1 * lda + k0 + sc, lA1);
    gl_lds16(Bt + br0 * ldb + k0 + sc, lB0);
    if (NB == 128) gl_lds16(Bt + br1 * ldb + k0 + sc, lB1);
    __syncthreads();
    u16x8 af[AF], bfr[BF];
#pragma unroll
    for (int i = 0; i < AF; i++) af[i] = *(const u16x8*)&smA[(wr + i * 16 + fr) * 32 + fk];
#pragma unroll
    for (int j = 0; j < BF; j++) bfr[j] = *(const u16x8*)&smB[(wc + j * 16 + fr) * 32 + fk];
#pragma unroll
    for (int i = 0; i < AF; i++)
#pragma unroll
      for (int j = 0; j < BF; j++) acc[i][j] = mfma16(af[i], bfr[j], acc[i][j]);
  }

#pragma unroll
  for (int i = 0; i < AF; i++) {
#pragma unroll
    for (int j = 0; j < BF; j++) {
#pragma unroll
      for (int e = 0; e < 4; e++) {
        int gr = m0 + wr + i * 16 + (ll >> 4) * 4 + e;
        int gc = n0 + wc + j * 16 + (ll & 15);
        if (gr < Mr && gc < Nr) {
          float v = acc[i][j][e];
          if (EPI & EPI_BIAS) v += bias[gc];
          long idx = coff + (long)gr * ldc + gc;
          if (EPI & EPI_OUTBF) ((unsigned short*)Call)[idx] = f2bu(v);
          else ((float*)Call)[idx] = v;
        }
      }
    }
  }
}

// ================= fused FAVOR+ kernels =================
DEVFN void feat_dd(const unsigned short* __restrict__ src, const unsigned short* __restrict__ projc,
                   unsigned short* ldsq, unsigned short* ldsp, int b, int t0, int hh,
                   f32x4 acc[16]) {
  int tid = threadIdx.x, wv = tid >> 6, ll = tid & 63;
#pragma unroll
  for (int p = 0; p < 2; p++) {
    int r = p * 64 + (tid >> 3), c8 = (tid & 7) * 8;
    *(u16x8*)&ldsq[r * 72 + c8] =
        *(const u16x8*)&src[((long)b * CT + t0 + r) * CQKV + hh * CDH + c8];
  }
#pragma unroll
  for (int p = 0; p < 4; p++) {
    int r = p * 64 + (tid >> 3), c8 = (tid & 7) * 8;
    *(u16x8*)&ldsp[r * 72 + c8] = *(const u16x8*)&projc[r * 64 + c8];
  }
  __syncthreads();
  int fr = ll & 15, fk = (ll >> 4) * 8;
#pragma unroll
  for (int ks = 0; ks < 2; ks++) {
    u16x8 af = *(const u16x8*)&ldsq[(wv * 16 + fr) * 72 + ks * 32 + fk];
#pragma unroll
    for (int j = 0; j < 16; j++) {
      u16x8 bf = *(const u16x8*)&ldsp[(j * 16 + fr) * 72 + ks * 32 + fk];
      acc[j] = mfma16(af, bf, acc[j]);
    }
  }
}

__global__ __launch_bounds__(512, 4) void kstab_f(const unsigned short* __restrict__ kb,
                                                  const unsigned short* __restrict__ projc,
                                                  float* __restrict__ part) {
  extern __shared__ char dynsm[];
  unsigned short* ldsq = (unsigned short*)dynsm;            // [128][72]
  unsigned short* ldsp = (unsigned short*)(dynsm + 18432);  // [256][72]
  __shared__ float smx[8];
  int bh = blockIdx.x >> 3, chunk = blockIdx.x & 7;
  int b = bh >> 4, hh = bh & 15;
  f32x4 acc[16] = {};
  feat_dd(kb, projc, ldsq, ldsp, b, chunk * 128, hh, acc);
  float mx = -3.4e38f;
#pragma unroll
  for (int j = 0; j < 16; j++)
#pragma unroll
    for (int e = 0; e < 4; e++) mx = fmaxf(mx, acc[j][e]);
  mx = wredmax(mx);
  int wv = threadIdx.x >> 6;
  if ((threadIdx.x & 63) == 0) smx[wv] = mx;
  __syncthreads();
  if (threadIdx.x == 0) {
    float m2 = smx[0];
#pragma unroll
    for (int i = 1; i < 8; i++) m2 = fmaxf(m2, smx[i]);
    part[blockIdx.x] = m2;
  }
}

__global__ __launch_bounds__(512, 4) void featk_f(const unsigned short* __restrict__ kb,
                                                  const unsigned short* __restrict__ projc,
                                                  const float* __restrict__ part,
                                                  unsigned short* __restrict__ kpt,
                                                  float* __restrict__ kspart) {
  extern __shared__ char dynsm[];
  unsigned short* ldsq = (unsigned short*)dynsm;            // [128][72]
  unsigned short* ldsp = (unsigned short*)(dynsm + 18432);  // [256][72]
  unsigned short* ldso = (unsigned short*)dynsm;            // overlay [256][136]
  int tid = threadIdx.x, wv = tid >> 6, ll = tid & 63;
  int bh = blockIdx.x >> 3, chunk = blockIdx.x & 7;
  int b = bh >> 4, hh = bh & 15;
  float st = part[bh * 8];
#pragma unroll
  for (int i = 1; i < 8; i++) st = fmaxf(st, part[bh * 8 + i]);
  f32x4 acc[16] = {};
  feat_dd(kb, projc, ldsq, ldsp, b, chunk * 128, hh, acc);
  int fr = ll & 15, g = ll >> 4;
  float diag[4];
#pragma unroll
  for (int e = 0; e < 4; e++) {
    int row = wv * 16 + g * 4 + e;
    u16x4 kv = *(const u16x4*)&ldsq[row * 72 + fr * 4];
    float s = 0;
#pragma unroll
    for (int z = 0; z < 4; z++) { float f = b2f(kv[z]); s += f * f; }
#pragma unroll
    for (int o = 1; o < 16; o <<= 1) s += __shfl_xor(s, o, 64);
    diag[e] = s * (0.5f * CDN * CDN);
  }
  __syncthreads();
#pragma unroll
  for (int j = 0; j < 16; j++)
#pragma unroll
    for (int e = 0; e < 4; e++) {
      float v = CRATIO * (expf(acc[j][e] - diag[e] - st) + CKEPS);
      ldso[(j * 16 + fr) * 136 + wv * 16 + g * 4 + e] = f2bu(v);
    }
  __syncthreads();
  int m = tid >> 1, seg = (tid & 1) * 64;
  long base = ((long)bh * CM + m) * CT + chunk * 128;
  float ks = 0;
#pragma unroll
  for (int z = 0; z < 8; z++) {
    u16x8 v8 = *(u16x8*)&ldso[m * 136 + seg + z * 8];
    *(u16x8*)&kpt[base + seg + z * 8] = v8;
#pragma unroll
    for (int w = 0; w < 8; w++) ks += b2f(v8[w]);
  }
  ks += __shfl_xor(ks, 1, 64);
  if ((tid & 1) == 0) kspart[((long)bh * 8 + chunk) * CM + m] = ks;
}

// queries fused to the end: dd -> qp (LDS) -> ksum-reduce -> dinv -> o = (qp@ctx)*dinv
__global__ __launch_bounds__(512, 4) void featqo_f(const unsigned short* __restrict__ qb,
                                                   const unsigned short* __restrict__ projc,
                                                   const float* __restrict__ kspart,
                                                   const unsigned short* __restrict__ ctxall,
                                                   unsigned short* __restrict__ obuf) {
  extern __shared__ char dynsm[];
  unsigned short* ldsq = (unsigned short*)dynsm;            // [128][72]
  unsigned short* ldsp = (unsigned short*)(dynsm + 18432);  // [256][72]
  unsigned short* ldso = (unsigned short*)dynsm;            // overlay [128][264] (t,m)
  float* ldks = (float*)(dynsm + 67584);                    // [256]
  float* ldinv = (float*)(dynsm + 68608);                   // [128]
  int tid = threadIdx.x, wv = tid >> 6, ll = tid & 63;
  int bh = blockIdx.x >> 3, chunk = blockIdx.x & 7;
  int b = bh >> 4, hh = bh & 15;
  int t0 = chunk * 128;
  if (tid < 256) {
    float s = 0;
#pragma unroll
    for (int c = 0; c < 8; c++) s += kspart[((long)bh * 8 + c) * CM + tid];
    ldks[tid] = s;
  }
  f32x4 acc[16] = {};
  feat_dd(qb, projc, ldsq, ldsp, b, t0, hh, acc);
  int fr = ll & 15, g = ll >> 4, fk = g * 8;
  float rmax[4], diag[4];
#pragma unroll
  for (int e = 0; e < 4; e++) {
    float mx = acc[0][e];
#pragma unroll
    for (int j = 1; j < 16; j++) mx = fmaxf(mx, acc[j][e]);
#pragma unroll
    for (int o = 1; o < 16; o <<= 1) mx = fmaxf(mx, __shfl_xor(mx, o, 64));
    rmax[e] = mx;
    int row = wv * 16 + g * 4 + e;
    u16x4 qv = *(const u16x4*)&ldsq[row * 72 + fr * 4];
    float s = 0;
#pragma unroll
    for (int z = 0; z < 4; z++) { float f = b2f(qv[z]); s += f * f; }
#pragma unroll
    for (int o = 1; o < 16; o <<= 1) s += __shfl_xor(s, o, 64);
    diag[e] = s * (0.5f * CDN * CDN);
  }
  __syncthreads();  // ldsq/ldsp reads done -> overlay write
#pragma unroll
  for (int j = 0; j < 16; j++)
#pragma unroll
    for (int e = 0; e < 4; e++) {
      float v = CRATIO * (expf(acc[j][e] - diag[e] - rmax[e]) + CKEPS);
      ldso[(wv * 16 + g * 4 + e) * 264 + j * 16 + fr] = f2bu(v);
    }
  __syncthreads();  // qp ready in LDS
  // dinv: dot(qp_row, ksum); 4 threads per row
  {
    int row = tid >> 2, seg = (tid & 3) * 64;
    float dot = 0;
#pragma unroll
    for (int z = 0; z < 8; z++) {
      u16x8 v8 = *(u16x8*)&ldso[row * 264 + seg + z * 8];
#pragma unroll
      for (int w = 0; w < 8; w++) dot += b2f(v8[w]) * ldks[seg + z * 8 + w];
    }
    dot += __shfl_xor(dot, 1, 64);
    dot += __shfl_xor(dot, 2, 64);
    if ((tid & 3) == 0) ldinv[row] = 1.0f / dot;
  }
  // o = qp(128x256) @ ctx^T; ctx stored (DH=64, M=256) == Bt(N,K); B-frags from L2
  const unsigned short* ctxb = ctxall + (long)bh * 16384;
  f32x4 ao[4] = {};
#pragma unroll
  for (int ks = 0; ks < 8; ks++) {
    u16x8 af = *(const u16x8*)&ldso[(wv * 16 + fr) * 264 + ks * 32 + fk];
#pragma unroll
    for (int j = 0; j < 4; j++) {
      u16x8 bf = *(const u16x8*)&ctxb[(j * 16 + fr) * 256 + ks * 32 + fk];
      ao[j] = mfma16(af, bf, ao[j]);
    }
  }
  __syncthreads();  // ldinv ready
#pragma unroll
  for (int j = 0; j < 4; j++)
#pragma unroll
    for (int e = 0; e < 4; e++) {
      int r = wv * 16 + g * 4 + e;
      float v = ao[j][e] * ldinv[r];
      obuf[((long)b * CT + t0 + r) * CDM + hh * CDH + j * 16 + fr] = f2bu(v);
    }
}

// ---------------- LayerNorm ----------------
__global__ __launch_bounds__(256) void ln_k(const float* __restrict__ h,
                                            const float* __restrict__ g,
                                            const float* __restrict__ b,
                                            unsigned short* __restrict__ y) {
  int wv = threadIdx.x >> 6, ll = threadIdx.x & 63;
  long row = (long)blockIdx.x * 4 + wv;
  const float* hr = h + row * CDM;
  f32x4 x[4];
#pragma unroll
  for (int i = 0; i < 4; i++) x[i] = *(const f32x4*)&hr[ll * 16 + i * 4];
  float s = 0;
#pragma unroll
  for (int i = 0; i < 4; i++)
#pragma unroll
    for (int e = 0; e < 4; e++) s += x[i][e];
  float mu = wredsum(s) * (1.f / CDM);
  float v = 0;
#pragma unroll
  for (int i = 0; i < 4; i++)
#pragma unroll
    for (int e = 0; e < 4; e++) {
      float d = x[i][e] - mu;
      v += d * d;
    }
  float inv = rsqrtf(wredsum(v) * (1.f / CDM) + 1e-5f);
  unsigned short o[16];
#pragma unroll
  for (int i = 0; i < 4; i++)
#pragma unroll
    for (int e = 0; e < 4; e++) {
      int c = ll * 16 + i * 4 + e;
      o[i * 4 + e] = f2bu((x[i][e] - mu) * inv * g[c] + b[c]);
    }
  *(u16x8*)&y[row * CDM + ll * 16] = *(u16x8*)&o[0];
  *(u16x8*)&y[row * CDM + ll * 16 + 8] = *(u16x8*)&o[8];
}

// ---------------- v -> v_t ----------------
__global__ __launch_bounds__(256) void trv_k(const unsigned short* __restrict__ vb,
                                             unsigned short* __restrict__ vt) {
  int bh = blockIdx.x >> 5;
  int t0 = (blockIdx.x & 31) * 32;
  int b = bh >> 4, hh = bh & 15;
  __shared__ unsigned short tile[32][64];
  int tr = threadIdx.x >> 3, dblk = (threadIdx.x & 7) * 8;
  *(u16x8*)&tile[tr][dblk] = *(const u16x8*)&vb[((long)b * CT + t0 + tr) * CQKV + hh * CDH + dblk];
  __syncthreads();
  int d = threadIdx.x >> 2, tz = (threadIdx.x & 3) * 8;
  unsigned short o[8];
#pragma unroll
  for (int e = 0; e < 8; e++) o[e] = tile[tz + e][d];
  *(u16x8*)&vt[((long)bh * CDH + d) * CT + t0 + tz] = *(u16x8*)&o[0];
}

// ---------------- fp32 -> bf16 flat ----------------
__global__ __launch_bounds__(256) void f2b_k(const float* __restrict__ in,
                                             unsigned short* __restrict__ out, long n) {
  long i = ((long)blockIdx.x * 256 + threadIdx.x) * 4;
  if (i >= n) return;
  f32x4 v = *(const f32x4*)&in[i];
  unsigned short o[4];
#pragma unroll
  for (int e = 0; e < 4; e++) o[e] = f2bu(v[e]);
  *(u16x4*)&out[i] = *(u16x4*)&o[0];
}

// ---------------- z-batched transpose-convert ----------------
__global__ __launch_bounds__(256) void tconvz_k(const float* __restrict__ in,
                                                unsigned short* __restrict__ out, int R, int C,
                                                long szs, long dzs) {
  const float* src = in + (long)blockIdx.z * szs;
  unsigned short* dst = out + (long)blockIdx.z * dzs;
  __shared__ float tile[32][33];
  int r0 = blockIdx.x * 32, c0 = blockIdx.y * 32;
  int tr = threadIdx.x >> 5, tc = threadIdx.x & 31;
#pragma unroll
  for (int p = 0; p < 4; p++) {
    int r = r0 + p * 8 + tr, c = c0 + tc;
    tile[p * 8 + tr][tc] = (r < R && c < C) ? src[(long)r * C + c] : 0.f;
  }
  __syncthreads();
#pragma unroll
  for (int p = 0; p < 4; p++) {
    int c = c0 + p * 8 + tr, r = r0 + tc;
    if (c < C && r < R) dst[(long)c * R + r] = f2bu(tile[tc][p * 8 + tr]);
  }
}

// ---------------- Wconv -> per-tap bf16: [r][oc][ic] = (192,1024) ----------------
__global__ __launch_bounds__(256) void wconv_k(const float* __restrict__ W,
                                               unsigned short* __restrict__ out) {
  int idx = blockIdx.x * 256 + threadIdx.x;
  int r = idx >> 16, rem = idx & 65535, oc = rem >> 10, ic = rem & 1023;
  out[idx] = f2bu(W[oc * 3072 + ic * 3 + r]);
}

// ---------------- conv tap-mix, EXACT zero-padding, bf16 out ----------------
__global__ __launch_bounds__(256) void convmix_k(const float* __restrict__ Y,
                                                 const float* __restrict__ bc,
                                                 unsigned short* __restrict__ xab) {
  long t = (long)blockIdx.x * 4 + (threadIdx.x >> 6);
  int oc = threadIdx.x & 63;
  int tb = (int)(t & 1023);
  float v = Y[t * 192 + 64 + oc] + bc[oc];
  if (tb != 0) v += Y[(t - 1) * 192 + oc];          // r=0 tap: zero at batch start
  if (tb != 1023) v += Y[(t + 1) * 192 + 128 + oc]; // r=2 tap: zero at batch end
  xab[t * 64 + oc] = f2bu(v);
}

// ---------------- proj * dn -> bf16 ----------------
__global__ __launch_bounds__(256) void projc_k(const float* __restrict__ p,
                                               unsigned short* __restrict__ out) {
  int i = blockIdx.x * 256 + threadIdx.x;
  out[i] = f2bu(p[i] * CDN);
}

// ---------------- concat q/k/v biases (z = layer) ----------------
__global__ __launch_bounds__(256) void catb_k(const float* __restrict__ q,
                                              const float* __restrict__ k,
                                              const float* __restrict__ v,
                                              float* __restrict__ o) {
  int l = blockIdx.y;
  int i = blockIdx.x * 256 + threadIdx.x;  // < 3072
  float val = i < 1024 ? q[l * CDM + i] : (i < 2048 ? k[l * CDM + i - 1024] : v[l * CDM + i - 2048]);
  o[l * CQKV + i] = val;
}

#define LAUNCH_GEMM(EPI, MB, NB, A, Bt, bias, C, Mr, Nr, Kr, lda, ldb, ldc, nb, bdiv, As1, As2, Bs1, Bs2, Cs1, Cs2) \
  gemm_k<EPI, MB, NB><<<dim3(((Mr) + (MB)-1) / (MB), ((Nr) + (NB)-1) / (NB), (nb)), 256, 0, stream>>>( \
      (const unsigned short*)(A), (const unsigned short*)(Bt), (bias), (void*)(C),               \
      (Mr), (Nr), (Kr), (lda), (ldb), (ldc), (bdiv), (long)(As1), (long)(As2), (long)(Bs1),      \
      (long)(Bs2), (long)(Cs1), (long)(Cs2))

#define LAUNCH_G1(EPI, A, Bt, bias, C, AUX, Mr, Nr, Kr, lda, ldb, ldc)                           \
  gemm128_k<EPI><<<dim3(((Mr) + 127) / 128, ((Nr) + 127) / 128), 512, 0, stream>>>(              \
      (const unsigned short*)(A), (const unsigned short*)(Bt), (bias), (void*)(C), (void*)(AUX), \
      (Mr), (Nr), (Kr), (lda), (ldb), (ldc))

extern "C" void kernel_launch(void* const* d_in, const int* in_sizes, int n_in,
                              void* d_out, int out_size, void* d_ws, size_t ws_size,
                              hipStream_t stream) {
  const float* x = (const float*)d_in[0];
  const float* Win = (const float*)d_in[1];
  const float* b_in = (const float*)d_in[2];
  const float* pe = (const float*)d_in[3];
  const float* ln1_g = (const float*)d_in[4];
  const float* ln1_b = (const float*)d_in[5];
  const float* Wq = (const float*)d_in[6];
  const float* bq = (const float*)d_in[7];
  const float* Wk = (const float*)d_in[8];
  const float* bk = (const float*)d_in[9];
  const float* Wv = (const float*)d_in[10];
  const float* bv = (const float*)d_in[11];
  const float* Wo = (const float*)d_in[12];
  const float* bo = (const float*)d_in[13];
  const float* ln2_g = (const float*)d_in[14];
  const float* ln2_b = (const float*)d_in[15];
  const float* W1 = (const float*)d_in[16];
  const float* b1 = (const float*)d_in[17];
  const float* W2 = (const float*)d_in[18];
  const float* b2 = (const float*)d_in[19];
  const float* Wc = (const float*)d_in[20];
  const float* bc = (const float*)d_in[21];
  const float* Wconv = (const float*)d_in[22];
  const float* bconv = (const float*)d_in[23];
  const float* Waux = (const float*)d_in[24];
  const float* baux = (const float*)d_in[25];
  const float* proj = (const float*)d_in[26];
  float* out = (float*)d_out;

  char* wsp = (char*)d_ws;
  size_t off = 0;
  auto take = [&](size_t bytes) {
    char* p = wsp + off;
    off = (off + bytes + 255) & ~(size_t)255;
    return p;
  };
  float* h_f = (float*)take(33554432);                      // (8192,1024) fp32 residual
  unsigned short* y_bf = (unsigned short*)take(16777216);   // LN out; aliased: vt, o
  unsigned short* qkv_bf = (unsigned short*)take(50331648); // (8192,3072) fused q,k,v
  unsigned short* kpt_bf = (unsigned short*)take(67108864); // (B,H,M,T)
  unsigned short* ff_bf = (unsigned short*)take(67108864);  // (8192,4096) FFN mid
  unsigned short* ctx_bf = (unsigned short*)take(4194304);  // (B,H,DH,M)
  float* kspart_f = (float*)take(1048576);                  // (bh,8,256)
  float* kstab_f_buf = (float*)take(4096);                  // (bh,8)
  float* ycv_f = (float*)take(6291456);                     // (8192,192) conv taps
  unsigned short* xabf = (unsigned short*)take(1048576);
  float* bqkv_f = (float*)take(24576);                      // 2 layers x 3072
  unsigned short* hbf = (unsigned short*)take(16777216);    // bf16 dual-write of h
  unsigned short* xbf = (unsigned short*)take(4194304);
  unsigned short* win_t = (unsigned short*)take(524288);
  unsigned short* wqkvo_t = (unsigned short*)take(16777216);
  unsigned short* w1_t = (unsigned short*)take(16777216);
  unsigned short* w2_t = (unsigned short*)take(16777216);
  unsigned short* wc_t = (unsigned short*)take(4096000);
  unsigned short* projc = (unsigned short*)take(32768);
  unsigned short* wconv_t = (unsigned short*)take(393216);
  unsigned short* waux_t = (unsigned short*)take(256128);
  unsigned short* vt_bf = y_bf;                    // alias (y dead after QKV)
  unsigned short* o_bf = y_bf;                     // alias (vt dead after ctx)
  (void)in_sizes; (void)n_in; (void)out_size; (void)ws_size;

  // ---- weight conversion (z-batched) ----
  f2b_k<<<2048, 256, 0, stream>>>(x, xbf, (long)CNT * 256);
  tconvz_k<<<dim3(8, 32, 1), 256, 0, stream>>>(Win, win_t, 256, 1024, 0, 0);
  tconvz_k<<<dim3(32, 32, 2), 256, 0, stream>>>(Wq, wqkvo_t + 0 * 1048576, 1024, 1024, 1048576, 4194304);
  tconvz_k<<<dim3(32, 32, 2), 256, 0, stream>>>(Wk, wqkvo_t + 1 * 1048576, 1024, 1024, 1048576, 4194304);
  tconvz_k<<<dim3(32, 32, 2), 256, 0, stream>>>(Wv, wqkvo_t + 2 * 1048576, 1024, 1024, 1048576, 4194304);
  tconvz_k<<<dim3(32, 32, 2), 256, 0, stream>>>(Wo, wqkvo_t + 3 * 1048576, 1024, 1024, 1048576, 4194304);
  tconvz_k<<<dim3(32, 128, 2), 256, 0, stream>>>(W1, w1_t, 1024, 4096, 4194304, 4194304);
  tconvz_k<<<dim3(128, 32, 2), 256, 0, stream>>>(W2, w2_t, 4096, 1024, 4194304, 4194304);
  tconvz_k<<<dim3(32, 63, 1), 256, 0, stream>>>(Wc, wc_t, 1024, 2000, 0, 0);
  tconvz_k<<<dim3(2, 63, 1), 256, 0, stream>>>(Waux, waux_t, 64, 2001, 0, 0);
  catb_k<<<dim3(12, 2), 256, 0, stream>>>(bq, bk, bv, bqkv_f);
  wconv_k<<<768, 256, 0, stream>>>(Wconv, wconv_t);
  projc_k<<<64, 256, 0, stream>>>(proj, projc);

  // ---- embed (+pe fused) ----
  LAUNCH_G1(EPI_BIAS | EPI_PE, xbf, win_t, b_in, h_f, pe, CNT, CDM, 256, 256, 256, CDM);

  for (int l = 0; l < 2; l++) {
    const unsigned short* wqkv_t = wqkvo_t + (long)(l * 4) * 1048576;  // q,k,v adjacent
    const unsigned short* wo_t = wqkvo_t + (long)(l * 4 + 3) * 1048576;

    ln_k<<<2048, 256, 0, stream>>>(h_f, ln1_g + l * CDM, ln1_b + l * CDM, y_bf);
    LAUNCH_G1(EPI_BIAS | EPI_OUTBF, y_bf, wqkv_t, bqkv_f + l * CQKV, qkv_bf, nullptr, CNT, CQKV, CDM, CDM, CDM, CQKV);

    // fused FAVOR+: keys (2 passes), v transpose, ctx GEMM, then fused queries+PV
    kstab_f<<<1024, 512, 55296, stream>>>(qkv_bf + 1024, projc, kstab_f_buf);
    featk_f<<<1024, 512, 69632, stream>>>(qkv_bf + 1024, projc, kstab_f_buf, kpt_bf, kspart_f);
    trv_k<<<4096, 256, 0, stream>>>(qkv_bf + 2048, vt_bf);
    LAUNCH_GEMM(EPI_OUTBF, 64, 128, vt_bf, kpt_bf, nullptr, ctx_bf, CDH, CM, CT, CT, CT, CM, 128, CH,
                (long)CH * CDH * CT, (long)CDH * CT, (long)CH * CM * CT, (long)CM * CT,
                (long)CH * CDH * CM, (long)CDH * CM);
    featqo_f<<<1024, 512, 69120, stream>>>(qkv_bf, projc, kspart_f, ctx_bf, o_bf);
    LAUNCH_G1(EPI_BIAS | EPI_ACCUM, o_bf, wo_t, bo + l * CDM, h_f, nullptr, CNT, CDM, CDM, CDM, CDM, CDM);

    ln_k<<<2048, 256, 0, stream>>>(h_f, ln2_g + l * CDM, ln2_b + l * CDM, y_bf);
    LAUNCH_G1(EPI_BIAS | EPI_GELU | EPI_OUTBF, y_bf, w1_t + (long)l * 4194304, b1 + l * CDFF, ff_bf, nullptr,
              CNT, CDFF, CDM, CDM, CDM, CDFF);
    LAUNCH_G1(EPI_BIAS | EPI_ACCUM | EPI_DUP, ff_bf, w2_t + (long)l * 4194304, b2 + l * CDM, h_f, hbf,
              CNT, CDM, CDFF, CDFF, CDFF, CDM);

    if (l == 0) {
      LAUNCH_GEMM(0, 128, 128, hbf, wconv_t, nullptr, ycv_f, CNT, 192, CDM, CDM, CDM, 192, 1, 1, 0, 0, 0, 0, 0, 0);
      convmix_k<<<2048, 256, 0, stream>>>(ycv_f, bconv, xabf);
      LAUNCH_GEMM(EPI_BIAS, 128, 128, xabf, waux_t, baux, out + 16384000, CNT, CV + 1, 64, 64, 64, CV + 1, 1, 1, 0, 0, 0, 0, 0, 0);
    }
  }

  // ---- classifier (hbf written by layer-1 FFN2 dual-store) ----
  LAUNCH_G1(EPI_BIAS, hbf, wc_t, bc, out, nullptr, CNT, CV, CDM, CDM, CDM, CV);
}

// Round 14
// 1137.677 us; speedup vs baseline: 1.2123x; 1.0262x over previous
//
#include <hip/hip_runtime.h>
#include <hip/hip_bf16.h>

typedef __attribute__((ext_vector_type(4))) float f32x4;
typedef __attribute__((ext_vector_type(8))) unsigned short u16x8;
typedef __attribute__((ext_vector_type(4))) unsigned short u16x4;
typedef __bf16 bf16x8 __attribute__((ext_vector_type(8)));

#define DEVFN static __device__ __forceinline__

constexpr int CB = 8, CT = 1024, CDM = 1024, CH = 16, CDH = 64, CDFF = 4096, CV = 2000, CM = 256;
constexpr int CNT = CB * CT; // 8192 tokens
constexpr int CQKV = 3072;   // fused qkv row stride
constexpr float CDN = 0.35355339059327373f;   // 64^-0.25
constexpr float CRATIO = 0.0625f;             // 256^-0.5
constexpr float CKEPS = 1e-4f;

DEVFN unsigned short f2bu(float x) {
  __hip_bfloat16 h = __float2bfloat16(x);
  return __builtin_bit_cast(unsigned short, h);
}
DEVFN float b2f(unsigned short u) {
  __hip_bfloat16 h = __builtin_bit_cast(__hip_bfloat16, u);
  return __bfloat162float(h);
}
DEVFN float wredsum(float s) {
#pragma unroll
  for (int ofs = 32; ofs; ofs >>= 1) s += __shfl_xor(s, ofs, 64);
  return s;
}
DEVFN float wredmax(float s) {
#pragma unroll
  for (int ofs = 32; ofs; ofs >>= 1) s = fmaxf(s, __shfl_xor(s, ofs, 64));
  return s;
}
DEVFN void gl_lds16(const void* g, void* l) {
  __builtin_amdgcn_global_load_lds(
      (const __attribute__((address_space(1))) unsigned int*)g,
      (__attribute__((address_space(3))) unsigned int*)l, 16, 0, 0);
}
DEVFN f32x4 mfma16(u16x8 a, u16x8 b, f32x4 c) {
  return __builtin_amdgcn_mfma_f32_16x16x32_bf16(
      __builtin_bit_cast(bf16x8, a), __builtin_bit_cast(bf16x8, b), c, 0, 0, 0);
}
// compiler-invisible LDS read; waits are manual (counted lgkmcnt)
DEVFN u16x8 lds_rd128(unsigned addr) {
  u16x8 r;
  asm volatile("ds_read_b128 %0, %1" : "=v"(r) : "v"(addr));
  return r;
}
DEVFN unsigned lds_addr(const void* p) {
  return (unsigned)(unsigned long)(const __attribute__((address_space(3))) char*)p;
}

#define EPI_BIAS 1
#define EPI_ACCUM 2
#define EPI_GELU 4
#define EPI_OUTBF 8
#define EPI_PE 32    // add pe[(row&1023)*1024 + col] (aux = pe fp32)
#define EPI_DUP 64   // also write bf16 copy to aux at same idx

// ================= gemm32: 128x128, 8 waves (2x4), BK=32, 32 KB LDS =================
// Same skeleton as gemm128 (swizzle, asm reads, full-tile-lead prefetch, counted
// waits) but BK=32 halves LDS/block -> 3 blocks/CU @ launch_bounds(512,6): +50% TLP
// to hide the per-tile barrier/latency overhead. A/B vs gemm128 (QKV/FFN1 only).
template <int EPI>
__global__ __launch_bounds__(512, 6) void gemm32_k(
    const unsigned short* __restrict__ A, const unsigned short* __restrict__ Bt,
    const float* __restrict__ bias, void* __restrict__ C, void* __restrict__ aux,
    int Mr, int Nr, int Kr, int lda, int ldb, int ldc) {
  __shared__ unsigned short smA[2][128 * 32];  // 8 KB per buffer
  __shared__ unsigned short smB[2][128 * 32];

  int tid = threadIdx.x, wv = tid >> 6, ll = tid & 63;
  int wm = wv >> 2, wn = wv & 3;  // 2 x 4 wave grid; per-wave out 64x32
  int m0 = blockIdx.x * 128, n0 = blockIdx.y * 128;
  int fr = ll & 15, f16 = ll >> 4, fk = f16 * 8;

  const char* Ab = (const char*)A;
  const char* Bb = (const char*)Bt;

  // single 8 KB staging unit per operand: L = tid*16 bytes, pre-swizzled source
  unsigned int offA, offB;
  {
    int L = tid * 16;
    int P = L ^ (((L >> 9) & 1) << 5);
    int r = P >> 6, cb = P & 63;
    long rowA = min(m0 + r, Mr - 1);
    offA = (unsigned)(rowA * lda * 2 + cb);
    long rowB = min(n0 + r, Nr - 1);
    offB = (unsigned)(rowB * ldb * 2 + cb);
  }
  unsigned aAb = lds_addr(&smA[0][0]), aBb = lds_addr(&smB[0][0]);
  unsigned offArd[4], offBrd[2];
#pragma unroll
  for (int i = 0; i < 4; i++) {
    int r = wm * 64 + i * 16 + fr;
    offArd[i] = aAb + (unsigned)(r * 64 + 2 * (fk ^ (((r >> 3) & 1) << 4)));
  }
#pragma unroll
  for (int j = 0; j < 2; j++) {
    int r = wn * 32 + j * 16 + fr;
    offBrd[j] = aBb + (unsigned)(r * 64 + 2 * (fk ^ (((r >> 3) & 1) << 4)));
  }

  f32x4 acc[4][2] = {};
  int NT = Kr / 32;  // even for all our shapes

#define STG32(PB, KBN)                                                       \
  {                                                                          \
    gl_lds16(Ab + offA + (KBN), &smA[PB][tid * 8]);                          \
    gl_lds16(Bb + offB + (KBN), &smB[PB][tid * 8]);                          \
  }
#define TILE32(PB, KBN)                                                      \
  {                                                                          \
    __builtin_amdgcn_s_barrier(); /* readers of buf PB^1 done */             \
    __builtin_amdgcn_sched_barrier(0);                                       \
    STG32((PB) ^ 1, KBN);                                                    \
    asm volatile("s_waitcnt vmcnt(2)" ::: "memory");                         \
    __builtin_amdgcn_sched_barrier(0);                                       \
    __builtin_amdgcn_s_barrier(); /* buf PB globally ready */                \
    __builtin_amdgcn_sched_barrier(0);                                       \
    u16x8 a[4], b0, b1;                                                      \
    _Pragma("unroll") for (int i = 0; i < 4; i++)                            \
        a[i] = lds_rd128(offArd[i] + (PB)*8192);                             \
    b0 = lds_rd128(offBrd[0] + (PB)*8192);                                   \
    b1 = lds_rd128(offBrd[1] + (PB)*8192);                                   \
    asm volatile("s_waitcnt lgkmcnt(1)" ::: "memory");                       \
    __builtin_amdgcn_sched_barrier(0);                                       \
    __builtin_amdgcn_s_setprio(1);                                           \
    _Pragma("unroll") for (int i = 0; i < 4; i++)                            \
        acc[i][0] = mfma16(a[i], b0, acc[i][0]);                             \
    __builtin_amdgcn_s_setprio(0);                                           \
    asm volatile("s_waitcnt lgkmcnt(0)" ::: "memory");                       \
    __builtin_amdgcn_sched_barrier(0);                                       \
    __builtin_amdgcn_s_setprio(1);                                           \
    _Pragma("unroll") for (int i = 0; i < 4; i++)                            \
        acc[i][1] = mfma16(a[i], b1, acc[i][1]);                             \
    __builtin_amdgcn_s_setprio(0);                                           \
  }

  STG32(0, 0);  // prologue: tile 0 -> buf0
  for (int t = 0; t < NT; t += 2) {
    long kb1 = (long)(t + 1) * 64;
    long kb2 = (long)min(t + 2, NT - 1) * 64;
    TILE32(0, kb1);
    TILE32(1, kb2);
  }
  asm volatile("s_waitcnt vmcnt(0)" ::: "memory");  // drain dangling DMA
  __builtin_amdgcn_sched_barrier(0);
#undef TILE32
#undef STG32

#pragma unroll
  for (int i = 0; i < 4; i++) {
#pragma unroll
    for (int j = 0; j < 2; j++) {
#pragma unroll
      for (int e = 0; e < 4; e++) {
        int gr = m0 + wm * 64 + i * 16 + f16 * 4 + e;
        int gc = n0 + wn * 32 + j * 16 + fr;
        if (gr < Mr && gc < Nr) {
          float v = acc[i][j][e];
          if (EPI & EPI_BIAS) v += bias[gc];
          if (EPI & EPI_GELU) v = 0.5f * v * (1.0f + erff(v * 0.70710678118f));
          if (EPI & EPI_PE) v += ((const float*)aux)[((long)(gr & 1023) << 10) + gc];
          long idx = (long)gr * ldc + gc;
          if (EPI & EPI_ACCUM) v += ((float*)C)[idx];
          if (EPI & EPI_OUTBF) ((unsigned short*)C)[idx] = f2bu(v);
          else ((float*)C)[idx] = v;
          if (EPI & EPI_DUP) ((unsigned short*)aux)[idx] = f2bu(v);
        }
      }
    }
  }
}

// ================= 128x128 big GEMM, BK=64 (control; best measured 122 us) =================
template <int EPI>
__global__ __launch_bounds__(512, 4) void gemm128_k(
    const unsigned short* __restrict__ A, const unsigned short* __restrict__ Bt,
    const float* __restrict__ bias, void* __restrict__ C, void* __restrict__ aux,
    int Mr, int Nr, int Kr, int lda, int ldb, int ldc) {
  __shared__ unsigned short smA[2][128 * 64];
  __shared__ unsigned short smB[2][128 * 64];

  int tid = threadIdx.x, wv = tid >> 6, ll = tid & 63;
  int wm = wv >> 2, wn = wv & 3;  // 2 x 4 wave grid; per-wave out 64x32
  int m0 = blockIdx.x * 128, n0 = blockIdx.y * 128;
  int fr = ll & 15, f16 = ll >> 4, fk = f16 * 8;

  const char* Ab = (const char*)A;
  const char* Bb = (const char*)Bt;

  unsigned int offA[2], offB[2];
#pragma unroll
  for (int ro = 0; ro < 2; ro++) {
    int L = (ro * 512 + tid) * 16;
    int P = L ^ (((L >> 9) & 1) << 5);
    int kh = P >> 13, rem = P & 8191;
    int r = rem >> 6, cb = rem & 63;
    long rowA = min(m0 + r, Mr - 1);
    offA[ro] = (unsigned)((rowA * lda + kh * 32) * 2 + cb);
    long rowB = min(n0 + r, Nr - 1);
    offB[ro] = (unsigned)((rowB * ldb + kh * 32) * 2 + cb);
  }
  unsigned aAb = lds_addr(&smA[0][0]), aBb = lds_addr(&smB[0][0]);
  unsigned offArd[4], offBrd[2];
#pragma unroll
  for (int i = 0; i < 4; i++) {
    int r = wm * 64 + i * 16 + fr;
    offArd[i] = aAb + (unsigned)(r * 64 + 2 * (fk ^ (((r >> 3) & 1) << 4)));
  }
#pragma unroll
  for (int j = 0; j < 2; j++) {
    int r = wn * 32 + j * 16 + fr;
    offBrd[j] = aBb + (unsigned)(r * 64 + 2 * (fk ^ (((r >> 3) & 1) << 4)));
  }

  f32x4 acc[4][2] = {};
  int NT = Kr / 64;

#define STGALL(PB, KBN)                                                      \
  {                                                                          \
    _Pragma("unroll") for (int ro = 0; ro < 2; ro++)                         \
        gl_lds16(Ab + offA[ro] + (KBN), &smA[PB][(ro * 512 + wv * 64) * 8]); \
    _Pragma("unroll") for (int ro = 0; ro < 2; ro++)                         \
        gl_lds16(Bb + offB[ro] + (KBN), &smB[PB][(ro * 512 + wv * 64) * 8]); \
  }
#define TILE(PB, KBN)                                                        \
  {                                                                          \
    __builtin_amdgcn_s_barrier();                                            \
    __builtin_amdgcn_sched_barrier(0);                                       \
    STGALL((PB) ^ 1, KBN);                                                   \
    asm volatile("s_waitcnt vmcnt(4)" ::: "memory");                         \
    __builtin_amdgcn_sched_barrier(0);                                       \
    __builtin_amdgcn_s_barrier();                                            \
    __builtin_amdgcn_sched_barrier(0);                                       \
    u16x8 a0[4], b0[2], a1[4], b1[2];                                        \
    _Pragma("unroll") for (int i = 0; i < 4; i++)                            \
        a0[i] = lds_rd128(offArd[i] + (PB)*16384);                           \
    _Pragma("unroll") for (int j = 0; j < 2; j++)                            \
        b0[j] = lds_rd128(offBrd[j] + (PB)*16384);                           \
    _Pragma("unroll") for (int i = 0; i < 4; i++)                            \
        a1[i] = lds_rd128(offArd[i] + (PB)*16384 + 8192);                    \
    _Pragma("unroll") for (int j = 0; j < 2; j++)                            \
        b1[j] = lds_rd128(offBrd[j] + (PB)*16384 + 8192);                    \
    asm volatile("s_waitcnt lgkmcnt(6)" ::: "memory");                       \
    __builtin_amdgcn_sched_barrier(0);                                       \
    __builtin_amdgcn_s_setprio(1);                                           \
    _Pragma("unroll") for (int i = 0; i < 4; i++) {                          \
      acc[i][0] = mfma16(a0[i], b0[0], acc[i][0]);                           \
      acc[i][1] = mfma16(a0[i], b0[1], acc[i][1]);                           \
    }                                                                        \
    __builtin_amdgcn_s_setprio(0);                                           \
    asm volatile("s_waitcnt lgkmcnt(0)" ::: "memory");                       \
    __builtin_amdgcn_sched_barrier(0);                                       \
    __builtin_amdgcn_s_setprio(1);                                           \
    _Pragma("unroll") for (int i = 0; i < 4; i++) {                          \
      acc[i][0] = mfma16(a1[i], b1[0], acc[i][0]);                           \
      acc[i][1] = mfma16(a1[i], b1[1], acc[i][1]);                           \
    }                                                                        \
    __builtin_amdgcn_s_setprio(0);                                           \
  }

  STGALL(0, 0);
  for (int t = 0; t < NT; t += 2) {
    long kb1 = (long)(t + 1) * 128;
    long kb2 = (long)min(t + 2, NT - 1) * 128;
    TILE(0, kb1);
    TILE(1, kb2);
  }
  asm volatile("s_waitcnt vmcnt(0)" ::: "memory");
  __builtin_amdgcn_sched_barrier(0);
#undef TILE
#undef STGALL

#pragma unroll
  for (int i = 0; i < 4; i++) {
#pragma unroll
    for (int j = 0; j < 2; j++) {
#pragma unroll
      for (int e = 0; e < 4; e++) {
        int gr = m0 + wm * 64 + i * 16 + f16 * 4 + e;
        int gc = n0 + wn * 32 + j * 16 + fr;
        if (gr < Mr && gc < Nr) {
          float v = acc[i][j][e];
          if (EPI & EPI_BIAS) v += bias[gc];
          if (EPI & EPI_GELU) v = 0.5f * v * (1.0f + erff(v * 0.70710678118f));
          if (EPI & EPI_PE) v += ((const float*)aux)[((long)(gr & 1023) << 10) + gc];
          long idx = (long)gr * ldc + gc;
          if (EPI & EPI_ACCUM) v += ((float*)C)[idx];
          if (EPI & EPI_OUTBF) ((unsigned short*)C)[idx] = f2bu(v);
          else ((float*)C)[idx] = v;
          if (EPI & EPI_DUP) ((unsigned short*)aux)[idx] = f2bu(v);
        }
      }
    }
  }
}

// ================= legacy batched GEMM, shape-templated tile MB x NB =================
template <int EPI, int MB, int NB>
__global__ __launch_bounds__(256) void gemm_k(
    const unsigned short* __restrict__ Aall, const unsigned short* __restrict__ Btall,
    const float* __restrict__ bias, void* __restrict__ Call,
    int Mr, int Nr, int Kr, int lda, int ldb, int ldc, int bdiv,
    long As1, long As2, long Bs1, long Bs2, long Cs1, long Cs2) {
  __shared__ unsigned short smA[MB * 32];
  __shared__ unsigned short smB[NB * 32];
  constexpr int WRN = (MB == 128 && NB == 128) ? 2 : (MB == 128 ? 4 : 1);
  constexpr int WCN = 4 / WRN;
  constexpr int MT = MB / WRN, NTW = NB / WCN;
  constexpr int AF = MT / 16, BF = NTW / 16;
  int bz = blockIdx.z;
  const unsigned short* A = Aall + (long)(bz / bdiv) * As1 + (long)(bz % bdiv) * As2;
  const unsigned short* Bt = Btall + (long)(bz / bdiv) * Bs1 + (long)(bz % bdiv) * Bs2;
  long coff = (long)(bz / bdiv) * Cs1 + (long)(bz % bdiv) * Cs2;

  int tid = threadIdx.x, wv = tid >> 6, ll = tid & 63;
  int m0 = blockIdx.x * MB, n0 = blockIdx.y * NB;
  int sr = tid >> 2, sc = (tid & 3) * 8;
  long ar0 = min(m0 + sr, Mr - 1);
  long ar1 = (MB == 128) ? min(m0 + sr + 64, (long)Mr - 1) : 0;
  long br0 = min(n0 + sr, Nr - 1);
  long br1 = (NB == 128) ? min(n0 + sr + 64, (long)Nr - 1) : 0;
  unsigned short* lA0 = &smA[(wv * 16) * 32];
  unsigned short* lA1 = &smA[(64 + wv * 16) * 32];
  unsigned short* lB0 = &smB[(wv * 16) * 32];
  unsigned short* lB1 = &smB[(64 + wv * 16) * 32];

  f32x4 acc[AF][BF] = {};
  int wr = (WRN == 1) ? 0 : ((WRN == 2) ? (wv >> 1) * MT : wv * MT);
  int wc = (WCN == 1) ? 0 : ((WCN == 2) ? (wv & 1) * NTW : wv * NTW);
  int fr = ll & 15, fk = (ll >> 4) * 8;

  for (int k0 = 0; k0 < Kr; k0 += 32) {
    __syncthreads();
    gl_lds16(A + ar0 * lda + k0 + sc, lA0);
    if (MB == 128) gl_lds16(A + ar1 * lda + k0 + sc, lA1);
    gl_lds16(Bt + br0 * ldb + k0 + sc, lB0);
    if (NB == 128) gl_lds16(Bt + br1 * ldb + k0 + sc, lB1);
    __syncthreads();
    u16x8 af[AF], bfr[BF];
#pragma unroll
    for (int i = 0; i < AF; i++) af[i] = *(const u16x8*)&smA[(wr + i * 16 + fr) * 32 + fk];
#pragma unroll
    for (int j = 0; j < BF; j++) bfr[j] = *(const u16x8*)&smB[(wc + j * 16 + fr) * 32 + fk];
#pragma unroll
    for (int i = 0; i < AF; i++)
#pragma unroll
      for (int j = 0; j < BF; j++) acc[i][j] = mfma16(af[i], bfr[j], acc[i][j]);
  }

#pragma unroll
  for (int i = 0; i < AF; i++) {
#pragma unroll
    for (int j = 0; j < BF; j++) {
#pragma unroll
      for (int e = 0; e < 4; e++) {
        int gr = m0 + wr + i * 16 + (ll >> 4) * 4 + e;
        int gc = n0 + wc + j * 16 + (ll & 15);
        if (gr < Mr && gc < Nr) {
          float v = acc[i][j][e];
          if (EPI & EPI_BIAS) v += bias[gc];
          long idx = coff + (long)gr * ldc + gc;
          if (EPI & EPI_OUTBF) ((unsigned short*)Call)[idx] = f2bu(v);
          else ((float*)Call)[idx] = v;
        }
      }
    }
  }
}

// ================= fused FAVOR+ kernels =================
DEVFN void feat_dd(const unsigned short* __restrict__ src, const unsigned short* __restrict__ projc,
                   unsigned short* ldsq, unsigned short* ldsp, int b, int t0, int hh,
                   f32x4 acc[16]) {
  int tid = threadIdx.x, wv = tid >> 6, ll = tid & 63;
#pragma unroll
  for (int p = 0; p < 2; p++) {
    int r = p * 64 + (tid >> 3), c8 = (tid & 7) * 8;
    *(u16x8*)&ldsq[r * 72 + c8] =
        *(const u16x8*)&src[((long)b * CT + t0 + r) * CQKV + hh * CDH + c8];
  }
#pragma unroll
  for (int p = 0; p < 4; p++) {
    int r = p * 64 + (tid >> 3), c8 = (tid & 7) * 8;
    *(u16x8*)&ldsp[r * 72 + c8] = *(const u16x8*)&projc[r * 64 + c8];
  }
  __syncthreads();
  int fr = ll & 15, fk = (ll >> 4) * 8;
#pragma unroll
  for (int ks = 0; ks < 2; ks++) {
    u16x8 af = *(const u16x8*)&ldsq[(wv * 16 + fr) * 72 + ks * 32 + fk];
#pragma unroll
    for (int j = 0; j < 16; j++) {
      u16x8 bf = *(const u16x8*)&ldsp[(j * 16 + fr) * 72 + ks * 32 + fk];
      acc[j] = mfma16(af, bf, acc[j]);
    }
  }
}

// pass 1 (keys): partial max of dd per (bh, chunk) + fused v-transpose
__global__ __launch_bounds__(512, 4) void kstab_f(const unsigned short* __restrict__ kb,
                                                  const unsigned short* __restrict__ projc,
                                                  const unsigned short* __restrict__ vb,
                                                  float* __restrict__ part,
                                                  unsigned short* __restrict__ vt) {
  extern __shared__ char dynsm[];
  unsigned short* ldsq = (unsigned short*)dynsm;            // [128][72]
  unsigned short* ldsp = (unsigned short*)(dynsm + 18432);  // [256][72]
  __shared__ float smx[8];
  int tid = threadIdx.x;
  int bh = blockIdx.x >> 3, chunk = blockIdx.x & 7;
  int b = bh >> 4, hh = bh & 15;
  int t0 = chunk * 128;
  f32x4 acc[16] = {};
  feat_dd(kb, projc, ldsq, ldsp, b, t0, hh, acc);
  float mx = -3.4e38f;
#pragma unroll
  for (int j = 0; j < 16; j++)
#pragma unroll
    for (int e = 0; e < 4; e++) mx = fmaxf(mx, acc[j][e]);
  mx = wredmax(mx);
  int wv = tid >> 6;
  if ((tid & 63) == 0) smx[wv] = mx;
  __syncthreads();  // also fences all ldsq reads before v overlay
  if (tid == 0) {
    float m2 = smx[0];
#pragma unroll
    for (int i = 1; i < 8; i++) m2 = fmaxf(m2, smx[i]);
    part[blockIdx.x] = m2;
  }
  // fused v transpose: (t0..t0+127, d 0..63) -> vt[bh][d][t]
#pragma unroll
  for (int p = 0; p < 2; p++) {
    int r = p * 64 + (tid >> 3), c8 = (tid & 7) * 8;
    *(u16x8*)&ldsq[r * 72 + c8] =
        *(const u16x8*)&vb[((long)b * CT + t0 + r) * CQKV + hh * CDH + c8];
  }
  __syncthreads();
  int d = tid >> 3, tz = (tid & 7) * 16;
  unsigned short o1[8], o2[8];
#pragma unroll
  for (int e = 0; e < 8; e++) {
    o1[e] = ldsq[(tz + e) * 72 + d];
    o2[e] = ldsq[(tz + 8 + e) * 72 + d];
  }
  long vbase = ((long)bh * CDH + d) * CT + t0 + tz;
  *(u16x8*)&vt[vbase] = *(u16x8*)&o1[0];
  *(u16x8*)&vt[vbase + 8] = *(u16x8*)&o2[0];
}

__global__ __launch_bounds__(512, 4) void featk_f(const unsigned short* __restrict__ kb,
                                                  const unsigned short* __restrict__ projc,
                                                  const float* __restrict__ part,
                                                  unsigned short* __restrict__ kpt,
                                                  float* __restrict__ kspart) {
  extern __shared__ char dynsm[];
  unsigned short* ldsq = (unsigned short*)dynsm;            // [128][72]
  unsigned short* ldsp = (unsigned short*)(dynsm + 18432);  // [256][72]
  unsigned short* ldso = (unsigned short*)dynsm;            // overlay [256][136]
  int tid = threadIdx.x, wv = tid >> 6, ll = tid & 63;
  int bh = blockIdx.x >> 3, chunk = blockIdx.x & 7;
  int b = bh >> 4, hh = bh & 15;
  float st = part[bh * 8];
#pragma unroll
  for (int i = 1; i < 8; i++) st = fmaxf(st, part[bh * 8 + i]);
  f32x4 acc[16] = {};
  feat_dd(kb, projc, ldsq, ldsp, b, chunk * 128, hh, acc);
  int fr = ll & 15, g = ll >> 4;
  float diag[4];
#pragma unroll
  for (int e = 0; e < 4; e++) {
    int row = wv * 16 + g * 4 + e;
    u16x4 kv = *(const u16x4*)&ldsq[row * 72 + fr * 4];
    float s = 0;
#pragma unroll
    for (int z = 0; z < 4; z++) { float f = b2f(kv[z]); s += f * f; }
#pragma unroll
    for (int o = 1; o < 16; o <<= 1) s += __shfl_xor(s, o, 64);
    diag[e] = s * (0.5f * CDN * CDN);
  }
  __syncthreads();
#pragma unroll
  for (int j = 0; j < 16; j++)
#pragma unroll
    for (int e = 0; e < 4; e++) {
      float v = CRATIO * (expf(acc[j][e] - diag[e] - st) + CKEPS);
      ldso[(j * 16 + fr) * 136 + wv * 16 + g * 4 + e] = f2bu(v);
    }
  __syncthreads();
  int m = tid >> 1, seg = (tid & 1) * 64;
  long base = ((long)bh * CM + m) * CT + chunk * 128;
  float ks = 0;
#pragma unroll
  for (int z = 0; z < 8; z++) {
    u16x8 v8 = *(u16x8*)&ldso[m * 136 + seg + z * 8];
    *(u16x8*)&kpt[base + seg + z * 8] = v8;
#pragma unroll
    for (int w = 0; w < 8; w++) ks += b2f(v8[w]);
  }
  ks += __shfl_xor(ks, 1, 64);
  if ((tid & 1) == 0) kspart[((long)bh * 8 + chunk) * CM + m] = ks;
}

// queries fused: dd -> qp (LDS) -> ksum-reduce -> dinv -> o = (qp@ctx)*dinv
__global__ __launch_bounds__(512, 4) void featqo_f(const unsigned short* __restrict__ qb,
                                                   const unsigned short* __restrict__ projc,
                                                   const float* __restrict__ kspart,
                                                   const unsigned short* __restrict__ ctxall,
                                                   unsigned short* __restrict__ obuf) {
  extern __shared__ char dynsm[];
  unsigned short* ldsq = (unsigned short*)dynsm;            // [128][72]
  unsigned short* ldsp = (unsigned short*)(dynsm + 18432);  // [256][72]
  unsigned short* ldso = (unsigned short*)dynsm;            // overlay [128][264] (t,m)
  float* ldks = (float*)(dynsm + 67584);                    // [256]
  float* ldinv = (float*)(dynsm + 68608);                   // [128]
  int tid = threadIdx.x, wv = tid >> 6, ll = tid & 63;
  int bh = blockIdx.x >> 3, chunk = blockIdx.x & 7;
  int b = bh >> 4, hh = bh & 15;
  int t0 = chunk * 128;
  if (tid < 256) {
    float s = 0;
#pragma unroll
    for (int c = 0; c < 8; c++) s += kspart[((long)bh * 8 + c) * CM + tid];
    ldks[tid] = s;
  }
  f32x4 acc[16] = {};
  feat_dd(qb, projc, ldsq, ldsp, b, t0, hh, acc);
  int fr = ll & 15, g = ll >> 4, fk = g * 8;
  float rmax[4], diag[4];
#pragma unroll
  for (int e = 0; e < 4; e++) {
    float mx = acc[0][e];
#pragma unroll
    for (int j = 1; j < 16; j++) mx = fmaxf(mx, acc[j][e]);
#pragma unroll
    for (int o = 1; o < 16; o <<= 1) mx = fmaxf(mx, __shfl_xor(mx, o, 64));
    rmax[e] = mx;
    int row = wv * 16 + g * 4 + e;
    u16x4 qv = *(const u16x4*)&ldsq[row * 72 + fr * 4];
    float s = 0;
#pragma unroll
    for (int z = 0; z < 4; z++) { float f = b2f(qv[z]); s += f * f; }
#pragma unroll
    for (int o = 1; o < 16; o <<= 1) s += __shfl_xor(s, o, 64);
    diag[e] = s * (0.5f * CDN * CDN);
  }
  __syncthreads();
#pragma unroll
  for (int j = 0; j < 16; j++)
#pragma unroll
    for (int e = 0; e < 4; e++) {
      float v = CRATIO * (expf(acc[j][e] - diag[e] - rmax[e]) + CKEPS);
      ldso[(wv * 16 + g * 4 + e) * 264 + j * 16 + fr] = f2bu(v);
    }
  __syncthreads();
  {
    int row = tid >> 2, seg = (tid & 3) * 64;
    float dot = 0;
#pragma unroll
    for (int z = 0; z < 8; z++) {
      u16x8 v8 = *(u16x8*)&ldso[row * 264 + seg + z * 8];
#pragma unroll
      for (int w = 0; w < 8; w++) dot += b2f(v8[w]) * ldks[seg + z * 8 + w];
    }
    dot += __shfl_xor(dot, 1, 64);
    dot += __shfl_xor(dot, 2, 64);
    if ((tid & 3) == 0) ldinv[row] = 1.0f / dot;
  }
  const unsigned short* ctxb = ctxall + (long)bh * 16384;
  f32x4 ao[4] = {};
#pragma unroll
  for (int ks = 0; ks < 8; ks++) {
    u16x8 af = *(const u16x8*)&ldso[(wv * 16 + fr) * 264 + ks * 32 + fk];
#pragma unroll
    for (int j = 0; j < 4; j++) {
      u16x8 bf = *(const u16x8*)&ctxb[(j * 16 + fr) * 256 + ks * 32 + fk];
      ao[j] = mfma16(af, bf, ao[j]);
    }
  }
  __syncthreads();
#pragma unroll
  for (int j = 0; j < 4; j++)
#pragma unroll
    for (int e = 0; e < 4; e++) {
      int r = wv * 16 + g * 4 + e;
      float v = ao[j][e] * ldinv[r];
      obuf[((long)b * CT + t0 + r) * CDM + hh * CDH + j * 16 + fr] = f2bu(v);
    }
}

// ---------------- LayerNorm ----------------
__global__ __launch_bounds__(256) void ln_k(const float* __restrict__ h,
                                            const float* __restrict__ g,
                                            const float* __restrict__ b,
                                            unsigned short* __restrict__ y) {
  int wv = threadIdx.x >> 6, ll = threadIdx.x & 63;
  long row = (long)blockIdx.x * 4 + wv;
  const float* hr = h + row * CDM;
  f32x4 x[4];
#pragma unroll
  for (int i = 0; i < 4; i++) x[i] = *(const f32x4*)&hr[ll * 16 + i * 4];
  float s = 0;
#pragma unroll
  for (int i = 0; i < 4; i++)
#pragma unroll
    for (int e = 0; e < 4; e++) s += x[i][e];
  float mu = wredsum(s) * (1.f / CDM);
  float v = 0;
#pragma unroll
  for (int i = 0; i < 4; i++)
#pragma unroll
    for (int e = 0; e < 4; e++) {
      float d = x[i][e] - mu;
      v += d * d;
    }
  float inv = rsqrtf(wredsum(v) * (1.f / CDM) + 1e-5f);
  unsigned short o[16];
#pragma unroll
  for (int i = 0; i < 4; i++)
#pragma unroll
    for (int e = 0; e < 4; e++) {
      int c = ll * 16 + i * 4 + e;
      o[i * 4 + e] = f2bu((x[i][e] - mu) * inv * g[c] + b[c]);
    }
  *(u16x8*)&y[row * CDM + ll * 16] = *(u16x8*)&o[0];
  *(u16x8*)&y[row * CDM + ll * 16 + 8] = *(u16x8*)&o[8];
}

// ---------------- fp32 -> bf16 flat ----------------
__global__ __launch_bounds__(256) void f2b_k(const float* __restrict__ in,
                                             unsigned short* __restrict__ out, long n) {
  long i = ((long)blockIdx.x * 256 + threadIdx.x) * 4;
  if (i >= n) return;
  f32x4 v = *(const f32x4*)&in[i];
  unsigned short o[4];
#pragma unroll
  for (int e = 0; e < 4; e++) o[e] = f2bu(v[e]);
  *(u16x4*)&out[i] = *(u16x4*)&o[0];
}

// ---------------- z-batched transpose-convert ----------------
__global__ __launch_bounds__(256) void tconvz_k(const float* __restrict__ in,
                                                unsigned short* __restrict__ out, int R, int C,
                                                long szs, long dzs) {
  const float* src = in + (long)blockIdx.z * szs;
  unsigned short* dst = out + (long)blockIdx.z * dzs;
  __shared__ float tile[32][33];
  int r0 = blockIdx.x * 32, c0 = blockIdx.y * 32;
  int tr = threadIdx.x >> 5, tc = threadIdx.x & 31;
#pragma unroll
  for (int p = 0; p < 4; p++) {
    int r = r0 + p * 8 + tr, c = c0 + tc;
    tile[p * 8 + tr][tc] = (r < R && c < C) ? src[(long)r * C + c] : 0.f;
  }
  __syncthreads();
#pragma unroll
  for (int p = 0; p < 4; p++) {
    int c = c0 + p * 8 + tr, r = r0 + tc;
    if (c < C && r < R) dst[(long)c * R + r] = f2bu(tile[tc][p * 8 + tr]);
  }
}

// ---------------- 4-weight x 2-layer transpose-convert (z in [0,8)) ----------------
__global__ __launch_bounds__(256) void tconv4_k(const float* __restrict__ Wq,
                                                const float* __restrict__ Wk,
                                                const float* __restrict__ Wv,
                                                const float* __restrict__ Wo,
                                                unsigned short* __restrict__ out) {
  int w = blockIdx.z & 3, l = blockIdx.z >> 2;
  const float* src = (w == 0 ? Wq : w == 1 ? Wk : w == 2 ? Wv : Wo) + (long)l * 1048576;
  unsigned short* dst = out + ((long)l * 4 + w) * 1048576;
  __shared__ float tile[32][33];
  int r0 = blockIdx.x * 32, c0 = blockIdx.y * 32;
  int tr = threadIdx.x >> 5, tc = threadIdx.x & 31;
#pragma unroll
  for (int p = 0; p < 4; p++) {
    int r = r0 + p * 8 + tr, c = c0 + tc;
    tile[p * 8 + tr][tc] = src[(long)r * 1024 + c];
  }
  __syncthreads();
#pragma unroll
  for (int p = 0; p < 4; p++) {
    int c = c0 + p * 8 + tr, r = r0 + tc;
    dst[(long)c * 1024 + r] = f2bu(tile[tc][p * 8 + tr]);
  }
}

// ---------------- Wconv -> per-tap bf16: [r][oc][ic] = (192,1024) ----------------
__global__ __launch_bounds__(256) void wconv_k(const float* __restrict__ W,
                                               unsigned short* __restrict__ out) {
  int idx = blockIdx.x * 256 + threadIdx.x;
  int r = idx >> 16, rem = idx & 65535, oc = rem >> 10, ic = rem & 1023;
  out[idx] = f2bu(W[oc * 3072 + ic * 3 + r]);
}

// ---------------- conv tap-mix, EXACT zero-padding, bf16 out ----------------
__global__ __launch_bounds__(256) void convmix_k(const float* __restrict__ Y,
                                                 const float* __restrict__ bc,
                                                 unsigned short* __restrict__ xab) {
  long t = (long)blockIdx.x * 4 + (threadIdx.x >> 6);
  int oc = threadIdx.x & 63;
  int tb = (int)(t & 1023);
  float v = Y[t * 192 + 64 + oc] + bc[oc];
  if (tb != 0) v += Y[(t - 1) * 192 + oc];
  if (tb != 1023) v += Y[(t + 1) * 192 + 128 + oc];
  xab[t * 64 + oc] = f2bu(v);
}

// ---------------- proj * dn -> bf16 ----------------
__global__ __launch_bounds__(256) void projc_k(const float* __restrict__ p,
                                               unsigned short* __restrict__ out) {
  int i = blockIdx.x * 256 + threadIdx.x;
  out[i] = f2bu(p[i] * CDN);
}

// ---------------- concat q/k/v biases (z = layer) ----------------
__global__ __launch_bounds__(256) void catb_k(const float* __restrict__ q,
                                              const float* __restrict__ k,
                                              const float* __restrict__ v,
                                              float* __restrict__ o) {
  int l = blockIdx.y;
  int i = blockIdx.x * 256 + threadIdx.x;  // < 3072
  float val = i < 1024 ? q[l * CDM + i] : (i < 2048 ? k[l * CDM + i - 1024] : v[l * CDM + i - 2048]);
  o[l * CQKV + i] = val;
}

#define LAUNCH_GEMM(EPI, MB, NB, A, Bt, bias, C, Mr, Nr, Kr, lda, ldb, ldc, nb, bdiv, As1, As2, Bs1, Bs2, Cs1, Cs2) \
  gemm_k<EPI, MB, NB><<<dim3(((Mr) + (MB)-1) / (MB), ((Nr) + (NB)-1) / (NB), (nb)), 256, 0, stream>>>( \
      (const unsigned short*)(A), (const unsigned short*)(Bt), (bias), (void*)(C),               \
      (Mr), (Nr), (Kr), (lda), (ldb), (ldc), (bdiv), (long)(As1), (long)(As2), (long)(Bs1),      \
      (long)(Bs2), (long)(Cs1), (long)(Cs2))

#define LAUNCH_G1(EPI, A, Bt, bias, C, AUX, Mr, Nr, Kr, lda, ldb, ldc)                           \
  gemm128_k<EPI><<<dim3(((Mr) + 127) / 128, ((Nr) + 127) / 128), 512, 0, stream>>>(              \
      (const unsigned short*)(A), (const unsigned short*)(Bt), (bias), (void*)(C), (void*)(AUX), \
      (Mr), (Nr), (Kr), (lda), (ldb), (ldc))

#define LAUNCH_G32(EPI, A, Bt, bias, C, AUX, Mr, Nr, Kr, lda, ldb, ldc)                          \
  gemm32_k<EPI><<<dim3(((Mr) + 127) / 128, ((Nr) + 127) / 128), 512, 0, stream>>>(               \
      (const unsigned short*)(A), (const unsigned short*)(Bt), (bias), (void*)(C), (void*)(AUX), \
      (Mr), (Nr), (Kr), (lda), (ldb), (ldc))

extern "C" void kernel_launch(void* const* d_in, const int* in_sizes, int n_in,
                              void* d_out, int out_size, void* d_ws, size_t ws_size,
                              hipStream_t stream) {
  const float* x = (const float*)d_in[0];
  const float* Win = (const float*)d_in[1];
  const float* b_in = (const float*)d_in[2];
  const float* pe = (const float*)d_in[3];
  const float* ln1_g = (const float*)d_in[4];
  const float* ln1_b = (const float*)d_in[5];
  const float* Wq = (const float*)d_in[6];
  const float* bq = (const float*)d_in[7];
  const float* Wk = (const float*)d_in[8];
  const float* bk = (const float*)d_in[9];
  const float* Wv = (const float*)d_in[10];
  const float* bv = (const float*)d_in[11];
  const float* Wo = (const float*)d_in[12];
  const float* bo = (const float*)d_in[13];
  const float* ln2_g = (const float*)d_in[14];
  const float* ln2_b = (const float*)d_in[15];
  const float* W1 = (const float*)d_in[16];
  const float* b1 = (const float*)d_in[17];
  const float* W2 = (const float*)d_in[18];
  const float* b2 = (const float*)d_in[19];
  const float* Wc = (const float*)d_in[20];
  const float* bc = (const float*)d_in[21];
  const float* Wconv = (const float*)d_in[22];
  const float* bconv = (const float*)d_in[23];
  const float* Waux = (const float*)d_in[24];
  const float* baux = (const float*)d_in[25];
  const float* proj = (const float*)d_in[26];
  float* out = (float*)d_out;

  char* wsp = (char*)d_ws;
  size_t off = 0;
  auto take = [&](size_t bytes) {
    char* p = wsp + off;
    off = (off + bytes + 255) & ~(size_t)255;
    return p;
  };
  float* h_f = (float*)take(33554432);                      // (8192,1024) fp32 residual
  unsigned short* y_bf = (unsigned short*)take(16777216);   // LN out; aliased: vt, o
  unsigned short* qkv_bf = (unsigned short*)take(50331648); // (8192,3072) fused q,k,v
  unsigned short* kpt_bf = (unsigned short*)take(67108864); // (B,H,M,T)
  unsigned short* ff_bf = (unsigned short*)take(67108864);  // (8192,4096) FFN mid
  unsigned short* ctx_bf = (unsigned short*)take(4194304);  // (B,H,DH,M)
  float* kspart_f = (float*)take(1048576);                  // (bh,8,256)
  float* kstab_f_buf = (float*)take(4096);                  // (bh,8)
  float* ycv_f = (float*)take(6291456);                     // (8192,192) conv taps
  unsigned short* xabf = (unsigned short*)take(1048576);
  float* bqkv_f = (float*)take(24576);                      // 2 layers x 3072
  unsigned short* hbf = (unsigned short*)take(16777216);    // bf16 dual-write of h
  unsigned short* xbf = (unsigned short*)take(4194304);
  unsigned short* win_t = (unsigned short*)take(524288);
  unsigned short* wqkvo_t = (unsigned short*)take(16777216);
  unsigned short* w1_t = (unsigned short*)take(16777216);
  unsigned short* w2_t = (unsigned short*)take(16777216);
  unsigned short* wc_t = (unsigned short*)take(4096000);
  unsigned short* projc = (unsigned short*)take(32768);
  unsigned short* wconv_t = (unsigned short*)take(393216);
  unsigned short* waux_t = (unsigned short*)take(256128);
  unsigned short* vt_bf = y_bf;                    // alias (y dead after QKV)
  unsigned short* o_bf = y_bf;                     // alias (vt dead after ctx)
  (void)in_sizes; (void)n_in; (void)out_size; (void)ws_size;

  // ---- weight conversion (z-batched / merged) ----
  f2b_k<<<2048, 256, 0, stream>>>(x, xbf, (long)CNT * 256);
  tconvz_k<<<dim3(8, 32, 1), 256, 0, stream>>>(Win, win_t, 256, 1024, 0, 0);
  tconv4_k<<<dim3(32, 32, 8), 256, 0, stream>>>(Wq, Wk, Wv, Wo, wqkvo_t);
  tconvz_k<<<dim3(32, 128, 2), 256, 0, stream>>>(W1, w1_t, 1024, 4096, 4194304, 4194304);
  tconvz_k<<<dim3(128, 32, 2), 256, 0, stream>>>(W2, w2_t, 4096, 1024, 4194304, 4194304);
  tconvz_k<<<dim3(32, 63, 1), 256, 0, stream>>>(Wc, wc_t, 1024, 2000, 0, 0);
  tconvz_k<<<dim3(2, 63, 1), 256, 0, stream>>>(Waux, waux_t, 64, 2001, 0, 0);
  catb_k<<<dim3(12, 2), 256, 0, stream>>>(bq, bk, bv, bqkv_f);
  wconv_k<<<768, 256, 0, stream>>>(Wconv, wconv_t);
  projc_k<<<64, 256, 0, stream>>>(proj, projc);

  // ---- embed (+pe fused) ----
  LAUNCH_G1(EPI_BIAS | EPI_PE, xbf, win_t, b_in, h_f, pe, CNT, CDM, 256, 256, 256, CDM);

  for (int l = 0; l < 2; l++) {
    const unsigned short* wqkv_t = wqkvo_t + (long)(l * 4) * 1048576;  // q,k,v adjacent
    const unsigned short* wo_t = wqkvo_t + (long)(l * 4 + 3) * 1048576;

    ln_k<<<2048, 256, 0, stream>>>(h_f, ln1_g + l * CDM, ln1_b + l * CDM, y_bf);
    // QKV on gemm32 (A/B vs gemm128 on FFN2/Wo/classifier)
    LAUNCH_G32(EPI_BIAS | EPI_OUTBF, y_bf, wqkv_t, bqkv_f + l * CQKV, qkv_bf, nullptr, CNT, CQKV, CDM, CDM, CDM, CQKV);

    // fused FAVOR+: keys (2 passes, v-transpose folded into pass 1), ctx GEMM, queries+PV
    kstab_f<<<1024, 512, 55296, stream>>>(qkv_bf + 1024, projc, qkv_bf + 2048, kstab_f_buf, vt_bf);
    featk_f<<<1024, 512, 69632, stream>>>(qkv_bf + 1024, projc, kstab_f_buf, kpt_bf, kspart_f);
    LAUNCH_GEMM(EPI_OUTBF, 64, 128, vt_bf, kpt_bf, nullptr, ctx_bf, CDH, CM, CT, CT, CT, CM, 128, CH,
                (long)CH * CDH * CT, (long)CDH * CT, (long)CH * CM * CT, (long)CM * CT,
                (long)CH * CDH * CM, (long)CDH * CM);
    featqo_f<<<1024, 512, 69120, stream>>>(qkv_bf, projc, kspart_f, ctx_bf, o_bf);
    LAUNCH_G1(EPI_BIAS | EPI_ACCUM, o_bf, wo_t, bo + l * CDM, h_f, nullptr, CNT, CDM, CDM, CDM, CDM, CDM);

    ln_k<<<2048, 256, 0, stream>>>(h_f, ln2_g + l * CDM, ln2_b + l * CDM, y_bf);
    // FFN1 on gemm32
    LAUNCH_G32(EPI_BIAS | EPI_GELU | EPI_OUTBF, y_bf, w1_t + (long)l * 4194304, b1 + l * CDFF, ff_bf, nullptr,
               CNT, CDFF, CDM, CDM, CDM, CDFF);
    LAUNCH_G1(EPI_BIAS | EPI_ACCUM | EPI_DUP, ff_bf, w2_t + (long)l * 4194304, b2 + l * CDM, h_f, hbf,
              CNT, CDM, CDFF, CDFF, CDFF, CDM);

    if (l == 0) {
      LAUNCH_GEMM(0, 128, 128, hbf, wconv_t, nullptr, ycv_f, CNT, 192, CDM, CDM, CDM, 192, 1, 1, 0, 0, 0, 0, 0, 0);
      convmix_k<<<2048, 256, 0, stream>>>(ycv_f, bconv, xabf);
      LAUNCH_GEMM(EPI_BIAS, 128, 128, xabf, waux_t, baux, out + 16384000, CNT, CV + 1, 64, 64, 64, CV + 1, 1, 1, 0, 0, 0, 0, 0, 0);
    }
  }

  // ---- classifier (hbf written by layer-1 FFN2 dual-store) ----
  LAUNCH_G1(EPI_BIAS, hbf, wc_t, bc, out, nullptr, CNT, CV, CDM, CDM, CDM, CV);
}